// Round 5
// baseline (2556.978 us; speedup 1.0000x reference)
//
#include <hip/hip_runtime.h>
#include <math.h>

#define NB 128      // B
#define NT 12       // T
#define NNODE 207   // N
#define NF 14       // F
#define NH 128      // H
#define ROWS (NB*NNODE)      // 26496
#define BTN (NB*NT*NNODE)    // 317952
#define G3 (3*NH)            // 384
#define LSTR 208             // padded Laplacian row stride
#define ZSTR 80              // padded z row stride (65 -> 80, 5 chunks of 16)

__device__ __forceinline__ float sigf(float x){ return 1.0f/(1.0f+__expf(-x)); }

__global__ __launch_bounds__(256) void k_sentinel(float* __restrict__ out, int n){
  int i = blockIdx.x*256 + threadIdx.x;
  if (i < n) out[i] = 12345.0f;
}

// packed transposed weights:
// WENC: 208x384 (rows 0..64 = ewih^T, 65..79 = 0, 80..207 = ewhh^T)
// DWHHT: 128x384 ; DWIHT: 32x384 (dwih cols 1..32) ; W0: 384 (dwih col 0)
#define OFF_WENC  0
#define OFF_DWHHT (208*384)
#define OFF_DWIHT (208*384 + 128*384)
#define OFF_W0    (208*384 + 128*384 + 32*384)
#define WT_TOTAL  (208*384 + 128*384 + 32*384 + 384)
__global__ __launch_bounds__(256) void k_prep(const float* __restrict__ ewih,
    const float* __restrict__ ewhh, const float* __restrict__ dwih,
    const float* __restrict__ dwhh, float* __restrict__ wt){
  int i = blockIdx.x*256 + threadIdx.x;
  if (i < OFF_DWHHT){
    int k = i/384, n = i%384;
    wt[i] = (k < 65) ? ewih[n*65 + k] : (k < 80 ? 0.f : ewhh[n*128 + (k-80)]);
  } else if (i < OFF_DWIHT){
    int j = i - OFF_DWHHT; int k = j/384, n = j%384;
    wt[i] = dwhh[n*128 + k];
  } else if (i < OFF_W0){
    int j = i - OFF_DWIHT; int k = j/384, n = j%384;
    wt[i] = dwih[n*33 + 1 + k];
  } else if (i < WT_TOTAL){
    int n = i - OFF_W0;
    wt[i] = dwih[n*33];
  }
}

// emb = tanh(state * fc_w + fc_b)   (B,N,16)
__global__ __launch_bounds__(256) void k_emb(const float* __restrict__ x,
    const float* __restrict__ w, const float* __restrict__ b, float* __restrict__ emb){
  int idx = blockIdx.x*256 + threadIdx.x;
  if (idx >= ROWS*16) return;
  int j = idx & 15, row = idx >> 4;
  int bb = row / NNODE, n = row % NNODE;
  float s = x[((bb*NT + (NT-1))*NNODE + n)*NF];
  emb[idx] = tanhf(s*w[j] + b[j]);
}

// wave-per-row: A_dyn row, top-10 (tie->lowest idx), sparse softmax, blend, rowsum
__global__ __launch_bounds__(256) void k_adj(const float* __restrict__ emb,
    const float* __restrict__ Aph, const float* __restrict__ alp,
    float* __restrict__ Abuf, float* __restrict__ rsum){
  int wid = threadIdx.x >> 6, lane = threadIdx.x & 63;
  int row = blockIdx.x*4 + wid;
  int bb = row / NNODE, n = row % NNODE;
  const float4* er = (const float4*)(emb + (size_t)row*16);
  float4 e0 = er[0], e1 = er[1], e2 = er[2], e3 = er[3];
  float d[4];
  #pragma unroll
  for (int q=0;q<4;++q){
    int m = lane + q*64;
    float dd = -1.f;
    if (m < NNODE){
      const float4* em = (const float4*)(emb + (size_t)(bb*NNODE+m)*16);
      float4 m0 = em[0], m1 = em[1], m2 = em[2], m3 = em[3];
      dd = e0.x*m0.x + e0.y*m0.y + e0.z*m0.z + e0.w*m0.w
         + e1.x*m1.x + e1.y*m1.y + e1.z*m1.z + e1.w*m1.w
         + e2.x*m2.x + e2.y*m2.y + e2.z*m2.z + e2.w*m2.w
         + e3.x*m3.x + e3.y*m3.y + e3.z*m3.z + e3.w*m3.w;
      dd = dd > 0.f ? dd : 0.f;
    }
    d[q] = dd;
  }
  int km = 0;
  float vmax = 0.f;
  for (int it=0; it<10; ++it){
    float v = -1.f; int mi = 1<<20;
    #pragma unroll
    for (int q=0;q<4;++q){
      if (d[q] >= 0.f && !((km>>q)&1) && d[q] > v){ v = d[q]; mi = lane + q*64; }
    }
    #pragma unroll
    for (int off=1; off<64; off<<=1){
      float v2 = __shfl_xor(v, off, 64);
      int  i2 = __shfl_xor(mi, off, 64);
      if (v2 > v || (v2 == v && i2 < mi)){ v = v2; mi = i2; }
    }
    if (it == 0) vmax = v;
    if ((mi & 63) == lane) km |= 1 << (mi >> 6);
  }
  float a = sigf(alp[0]);
  float eneg = __expf(-vmax);
  float p[4]; float ps = 0.f;
  #pragma unroll
  for (int q=0;q<4;++q){
    p[q] = 0.f;
    if (d[q] >= 0.f) p[q] = ((km>>q)&1) ? __expf(d[q]-vmax) : eneg;
    ps += p[q];
  }
  #pragma unroll
  for (int off=1; off<64; off<<=1) ps += __shfl_xor(ps, off, 64);
  float inv = (1.f - a)/ps;
  float rs = 0.f;
  #pragma unroll
  for (int q=0;q<4;++q){
    int m = lane + q*64;
    if (m < NNODE){
      float Av = a*Aph[n*NNODE + m] + p[q]*inv;
      Abuf[(size_t)row*LSTR + m] = Av;
      rs += Av;
    }
  }
  if (lane == 0) Abuf[(size_t)row*LSTR + 207] = 0.f;   // pad col
  #pragma unroll
  for (int off=1; off<64; off<<=1) rs += __shfl_xor(rs, off, 64);
  if (lane == 0) rsum[row] = rs;
}

__global__ __launch_bounds__(256) void k_lam(const float* __restrict__ rsum, float* __restrict__ lam){
  __shared__ float rv[256];
  int b = blockIdx.x, tid = threadIdx.x;
  rv[tid] = (tid < NNODE) ? rsum[b*NNODE+tid] : -1e30f;
  __syncthreads();
  for (int s=128;s>0;s>>=1){ if (tid<s) rv[tid]=fmaxf(rv[tid],rv[tid+s]); __syncthreads(); }
  if (tid==0) lam[b] = fmaxf(rv[0], 1.0f);
}

__global__ __launch_bounds__(256) void k_lap(float* __restrict__ Abuf, const float* __restrict__ lam){
  int idx = blockIdx.x*256 + threadIdx.x;
  if (idx >= NB*NNODE*LSTR) return;
  int b = idx / (NNODE*LSTR);
  int rem = idx % (NNODE*LSTR);
  int n = rem / LSTR, m = rem % LSTR;
  Abuf[idx] = 2.f*Abuf[idx]/lam[b] - (n==m ? 1.f : 0.f);   // m==207: 0 stays 0
}

// causal conv(3) + GLU -> t_feat (B,T,N,32)
__global__ __launch_bounds__(256) void k_tcn(const float* __restrict__ x,
    const float* __restrict__ w, const float* __restrict__ bcn, float* __restrict__ tfeat){
  int idx = blockIdx.x*256 + threadIdx.x;
  if (idx >= BTN*32) return;
  int o = idx & 31; int r = idx >> 5;
  int n = r % NNODE, bt = r / NNODE, t = bt % NT, b = bt / NT;
  float t0 = (t>=2)? x[((size_t)(b*NT+t-2)*NNODE+n)*NF] : 0.f;
  float t1 = (t>=1)? x[((size_t)(b*NT+t-1)*NNODE+n)*NF] : 0.f;
  float t2 = x[((size_t)(b*NT+t)*NNODE+n)*NF];
  float P = bcn[o]    + w[o*3]*t0       + w[o*3+1]*t1       + w[o*3+2]*t2;
  float Q = bcn[o+32] + w[(o+32)*3]*t0  + w[(o+32)*3+1]*t1  + w[(o+32)*3+2]*t2;
  tfeat[(size_t)r*32 + o] = P * sigf(Q);
}

// RB = tfeat@th1 -> P2 ; RC = tfeat@th2 -> P1     layout (B, N, T*32)
__global__ __launch_bounds__(256) void k_thetaBC(const float* __restrict__ tfeat,
    const float* __restrict__ theta, float* __restrict__ P2, float* __restrict__ P1){
  __shared__ float thB[32][33], thC[32][33];
  __shared__ float tf[8][32];
  int tid = threadIdx.x;
  for (int i=tid; i<1024; i+=256){
    int f = i >> 5, o = i & 31;
    thB[o][f] = theta[1024+f*32+o]; thC[o][f] = theta[2048+f*32+o];
  }
  int rl = tid >> 5, o = tid & 31;
  int r = blockIdx.x*8 + rl;
  tf[rl][o] = tfeat[(size_t)r*32 + o];
  __syncthreads();
  float aB=0.f, aC=0.f;
  #pragma unroll
  for (int f=0; f<32; ++f){
    float t = tf[rl][f];
    aB += t*thB[o][f]; aC += t*thC[o][f];
  }
  int n = r % NNODE, bt = r / NNODE, t = bt % NT, b = bt / NT;
  size_t outi = (size_t)(b*NNODE+n)*G3 + t*32 + o;
  P2[outi]=aB; P1[outi]=aC;
}

// RA = tfeat@(th0-th2) -> P1
__global__ __launch_bounds__(256) void k_thetaA(const float* __restrict__ tfeat,
    const float* __restrict__ theta, float* __restrict__ P1){
  __shared__ float thA[32][33];
  __shared__ float tf[8][32];
  int tid = threadIdx.x;
  for (int i=tid; i<1024; i+=256){
    int f = i >> 5, o = i & 31;
    thA[o][f] = theta[f*32+o] - theta[2048+f*32+o];
  }
  int rl = tid >> 5, o = tid & 31;
  int r = blockIdx.x*8 + rl;
  tf[rl][o] = tfeat[(size_t)r*32 + o];
  __syncthreads();
  float aA=0.f;
  #pragma unroll
  for (int f=0; f<32; ++f) aA += tf[rl][f]*thA[o][f];
  int n = r % NNODE, bt = r / NNODE, t = bt % NT, b = bt / NT;
  P1[(size_t)(b*NNODE+n)*G3 + t*32 + o] = aA;
}

// ---- unified 128x128 GEMM: C = [alpha*](A @ B) + bias|beta*Y [relu]
__global__ __launch_bounds__(256) void gemm128(
    const float* __restrict__ Ab, int lda, long long sA,
    const float* __restrict__ Bb, long long sB,
    const float* __restrict__ bias,
    const float* __restrict__ Yb, long long sY, float alphaV, float betaV, int do_relu,
    float* __restrict__ Cb, long long sC, int M, int kchunks){
  __shared__ float As[16][132];
  __shared__ float Bs[16][132];
  int bz = blockIdx.z;
  const float* A = Ab + (size_t)bz*sA;
  const float* B = Bb + (size_t)bz*sB;
  float* C = Cb + (size_t)bz*sC;
  int n0 = blockIdx.x*128, m0 = blockIdx.y*128;
  int tid = threadIdx.x, tx = tid & 15, ty = tid >> 4;
  float acc[8][8] = {};
  int ar = tid & 127, ak = (tid >> 7)*8;
  int bk = tid >> 4, bn = (tid & 15)*8;
  for (int kc=0; kc<kchunks; ++kc){
    int k0 = kc*16;
    int m = m0 + ar;
    if (m < M){
      const float* ap = A + (size_t)m*lda + k0 + ak;
      float4 v0 = *(const float4*)ap, v1 = *(const float4*)(ap+4);
      As[ak+0][ar]=v0.x; As[ak+1][ar]=v0.y; As[ak+2][ar]=v0.z; As[ak+3][ar]=v0.w;
      As[ak+4][ar]=v1.x; As[ak+5][ar]=v1.y; As[ak+6][ar]=v1.z; As[ak+7][ar]=v1.w;
    } else {
      #pragma unroll
      for (int j=0;j<8;++j) As[ak+j][ar]=0.f;
    }
    const float* bp = B + (size_t)(k0+bk)*384 + n0 + bn;
    float4 w0_ = *(const float4*)bp, w1_ = *(const float4*)(bp+4);
    *(float4*)&Bs[bk][bn] = w0_; *(float4*)&Bs[bk][bn+4] = w1_;
    __syncthreads();
    #pragma unroll
    for (int kk=0;kk<16;++kk){
      float4 a0 = *(const float4*)&As[kk][ty*8];
      float4 a1 = *(const float4*)&As[kk][ty*8+4];
      float4 b0 = *(const float4*)&Bs[kk][tx*4];
      float4 b1 = *(const float4*)&Bs[kk][64+tx*4];
      float av[8] = {a0.x,a0.y,a0.z,a0.w,a1.x,a1.y,a1.z,a1.w};
      float bv[8] = {b0.x,b0.y,b0.z,b0.w,b1.x,b1.y,b1.z,b1.w};
      #pragma unroll
      for (int i=0;i<8;++i)
        #pragma unroll
        for (int j=0;j<8;++j) acc[i][j] += av[i]*bv[j];
    }
    __syncthreads();
  }
  if (bias){
    float bl[4], bh_[4];
    #pragma unroll
    for (int j=0;j<4;++j){ bl[j]=bias[n0+tx*4+j]; bh_[j]=bias[n0+64+tx*4+j]; }
    #pragma unroll
    for (int i=0;i<8;++i){
      int m2 = m0 + ty*8 + i; if (m2 >= M) continue;
      float4 s0, s1;
      s0.x=acc[i][0]+bl[0]; s0.y=acc[i][1]+bl[1]; s0.z=acc[i][2]+bl[2]; s0.w=acc[i][3]+bl[3];
      s1.x=acc[i][4]+bh_[0]; s1.y=acc[i][5]+bh_[1]; s1.z=acc[i][6]+bh_[2]; s1.w=acc[i][7]+bh_[3];
      *(float4*)&C[(size_t)m2*384 + n0 + tx*4] = s0;
      *(float4*)&C[(size_t)m2*384 + n0 + 64 + tx*4] = s1;
    }
  } else {
    const float* Y = Yb + (size_t)bz*sY;
    #pragma unroll
    for (int i=0;i<8;++i){
      int m2 = m0 + ty*8 + i; if (m2 >= M) continue;
      const float* yr = Y + (size_t)m2*384;
      float* cr = C + (size_t)m2*384;
      float4 y0 = *(const float4*)(yr + n0 + tx*4);
      float4 y1 = *(const float4*)(yr + n0 + 64 + tx*4);
      float4 s0, s1;
      s0.x = alphaV*acc[i][0] + betaV*y0.x; s0.y = alphaV*acc[i][1] + betaV*y0.y;
      s0.z = alphaV*acc[i][2] + betaV*y0.z; s0.w = alphaV*acc[i][3] + betaV*y0.w;
      s1.x = alphaV*acc[i][4] + betaV*y1.x; s1.y = alphaV*acc[i][5] + betaV*y1.y;
      s1.z = alphaV*acc[i][6] + betaV*y1.z; s1.w = alphaV*acc[i][7] + betaV*y1.w;
      if (do_relu){
        s0.x=fmaxf(s0.x,0.f); s0.y=fmaxf(s0.y,0.f); s0.z=fmaxf(s0.z,0.f); s0.w=fmaxf(s0.w,0.f);
        s1.x=fmaxf(s1.x,0.f); s1.y=fmaxf(s1.y,0.f); s1.z=fmaxf(s1.z,0.f); s1.w=fmaxf(s1.w,0.f);
      }
      *(float4*)(cr + n0 + tx*4) = s0;
      *(float4*)(cr + n0 + 64 + tx*4) = s1;
    }
  }
}

// ---- fully-fused encoder step: h' = GRU(z_t@wih^T+bih, h@whh^T+bhh, h)
// 64 rows x 384 cols, 256 threads, acc 8x12 (+ accN 8x4 for n-gate h-part)
// WENC rows 0..79 = wih^T (65..79 zero), rows 80..207 = whh^T
__global__ __launch_bounds__(256) void k_enc_fused2(float* __restrict__ h,
    const float* __restrict__ zt, const float* __restrict__ WENC,
    const float* __restrict__ bih, const float* __restrict__ bhh){
  __shared__ float As[16][68];
  __shared__ float Bs[16][388];
  int m0 = blockIdx.x*64;
  int tid = threadIdx.x, tx = tid & 31, ty = tid >> 5;
  float acc[8][12] = {};
  float accN[8][4] = {};
  int ar = tid & 63, akq = (tid >> 6)*4;
  int bkr = tid >> 4, bcc = (tid & 15)*4;
  for (int kc=0; kc<13; ++kc){
    int k0 = kc*16;
    {
      const float* ap = (kc < 5)
        ? zt + (size_t)(m0+ar)*ZSTR + k0 + akq
        : h  + (size_t)(m0+ar)*NH + (k0-80) + akq;
      float4 v = *(const float4*)ap;
      As[akq+0][ar]=v.x; As[akq+1][ar]=v.y; As[akq+2][ar]=v.z; As[akq+3][ar]=v.w;
      const float* bp = WENC + (size_t)(k0+bkr)*384 + bcc;
      *(float4*)&Bs[bkr][bcc]     = *(const float4*)(bp);
      *(float4*)&Bs[bkr][bcc+64]  = *(const float4*)(bp+64);
      *(float4*)&Bs[bkr][bcc+128] = *(const float4*)(bp+128);
      *(float4*)&Bs[bkr][bcc+192] = *(const float4*)(bp+192);
      *(float4*)&Bs[bkr][bcc+256] = *(const float4*)(bp+256);
      *(float4*)&Bs[bkr][bcc+320] = *(const float4*)(bp+320);
    }
    __syncthreads();
    if (kc < 5){
      #pragma unroll
      for (int kk=0;kk<16;++kk){
        float4 a0 = *(const float4*)&As[kk][ty*8];
        float4 a1 = *(const float4*)&As[kk][ty*8+4];
        float4 b0 = *(const float4*)&Bs[kk][tx*4];
        float4 b1 = *(const float4*)&Bs[kk][tx*4+128];
        float4 b2 = *(const float4*)&Bs[kk][tx*4+256];
        float av[8] = {a0.x,a0.y,a0.z,a0.w,a1.x,a1.y,a1.z,a1.w};
        float bv[12] = {b0.x,b0.y,b0.z,b0.w,b1.x,b1.y,b1.z,b1.w,b2.x,b2.y,b2.z,b2.w};
        #pragma unroll
        for (int i=0;i<8;++i)
          #pragma unroll
          for (int j=0;j<12;++j) acc[i][j] += av[i]*bv[j];
      }
    } else {
      #pragma unroll
      for (int kk=0;kk<16;++kk){
        float4 a0 = *(const float4*)&As[kk][ty*8];
        float4 a1 = *(const float4*)&As[kk][ty*8+4];
        float4 b0 = *(const float4*)&Bs[kk][tx*4];
        float4 b1 = *(const float4*)&Bs[kk][tx*4+128];
        float4 b2 = *(const float4*)&Bs[kk][tx*4+256];
        float av[8] = {a0.x,a0.y,a0.z,a0.w,a1.x,a1.y,a1.z,a1.w};
        float bv[8] = {b0.x,b0.y,b0.z,b0.w,b1.x,b1.y,b1.z,b1.w};
        float nv[4] = {b2.x,b2.y,b2.z,b2.w};
        #pragma unroll
        for (int i=0;i<8;++i){
          #pragma unroll
          for (int j=0;j<8;++j) acc[i][j] += av[i]*bv[j];
          #pragma unroll
          for (int j=0;j<4;++j) accN[i][j] += av[i]*nv[j];
        }
      }
    }
    __syncthreads();
  }
  int jc = tx*4;
  float4 bir = *(const float4*)&bih[jc];
  float4 biz = *(const float4*)&bih[jc+128];
  float4 bin = *(const float4*)&bih[jc+256];
  float4 bhr = *(const float4*)&bhh[jc];
  float4 bhz = *(const float4*)&bhh[jc+128];
  float4 bhn = *(const float4*)&bhh[jc+256];
  #pragma unroll
  for (int rr=0;rr<8;++rr){
    int row = m0 + ty*8 + rr;
    float4 hv = *(float4*)&h[(size_t)row*NH + jc];
    float r_, z_, n_;
    r_ = sigf(acc[rr][0] + bir.x + bhr.x); z_ = sigf(acc[rr][4] + biz.x + bhz.x);
    n_ = tanhf(acc[rr][8]  + bin.x + r_*(accN[rr][0] + bhn.x)); hv.x = (1.f-z_)*n_ + z_*hv.x;
    r_ = sigf(acc[rr][1] + bir.y + bhr.y); z_ = sigf(acc[rr][5] + biz.y + bhz.y);
    n_ = tanhf(acc[rr][9]  + bin.y + r_*(accN[rr][1] + bhn.y)); hv.y = (1.f-z_)*n_ + z_*hv.y;
    r_ = sigf(acc[rr][2] + bir.z + bhr.z); z_ = sigf(acc[rr][6] + biz.z + bhz.z);
    n_ = tanhf(acc[rr][10] + bin.z + r_*(accN[rr][2] + bhn.z)); hv.z = (1.f-z_)*n_ + z_*hv.z;
    r_ = sigf(acc[rr][3] + bir.w + bhr.w); z_ = sigf(acc[rr][7] + biz.w + bhz.w);
    n_ = tanhf(acc[rr][11] + bin.w + r_*(accN[rr][3] + bhn.w)); hv.w = (1.f-z_)*n_ + z_*hv.w;
    *(float4*)&h[(size_t)row*NH + jc] = hv;
  }
}

// ---- fused decoder step: gh GEMM (K=128) + GRU + out-dot, pred chain
__global__ __launch_bounds__(256) void k_dec_fused2(float* __restrict__ h,
    const float* __restrict__ BT, const float* __restrict__ dbhh,
    const float* __restrict__ ctxGX, const float* __restrict__ w0,
    const float* __restrict__ ow, const float* __restrict__ ob,
    float* __restrict__ pred, float* __restrict__ preds_out){
  __shared__ float As[16][68];
  __shared__ float Bs[16][388];
  int m0 = blockIdx.x*64;
  int tid = threadIdx.x, tx = tid & 31, ty = tid >> 5;
  float acc[8][12] = {};
  int ar = tid & 63, akq = (tid >> 6)*4;
  int bkr = tid >> 4, bcc = (tid & 15)*4;
  for (int kc=0; kc<8; ++kc){
    int k0 = kc*16;
    {
      float4 v = *(const float4*)&h[(size_t)(m0+ar)*NH + k0 + akq];
      As[akq+0][ar]=v.x; As[akq+1][ar]=v.y; As[akq+2][ar]=v.z; As[akq+3][ar]=v.w;
      const float* bp = BT + (size_t)(k0+bkr)*384 + bcc;
      *(float4*)&Bs[bkr][bcc]     = *(const float4*)(bp);
      *(float4*)&Bs[bkr][bcc+64]  = *(const float4*)(bp+64);
      *(float4*)&Bs[bkr][bcc+128] = *(const float4*)(bp+128);
      *(float4*)&Bs[bkr][bcc+192] = *(const float4*)(bp+192);
      *(float4*)&Bs[bkr][bcc+256] = *(const float4*)(bp+256);
      *(float4*)&Bs[bkr][bcc+320] = *(const float4*)(bp+320);
    }
    __syncthreads();
    #pragma unroll
    for (int kk=0;kk<16;++kk){
      float4 a0 = *(const float4*)&As[kk][ty*8];
      float4 a1 = *(const float4*)&As[kk][ty*8+4];
      float4 b0 = *(const float4*)&Bs[kk][tx*4];
      float4 b1 = *(const float4*)&Bs[kk][tx*4+128];
      float4 b2 = *(const float4*)&Bs[kk][tx*4+256];
      float av[8] = {a0.x,a0.y,a0.z,a0.w,a1.x,a1.y,a1.z,a1.w};
      float bv[12] = {b0.x,b0.y,b0.z,b0.w,b1.x,b1.y,b1.z,b1.w,b2.x,b2.y,b2.z,b2.w};
      #pragma unroll
      for (int i=0;i<8;++i)
        #pragma unroll
        for (int j=0;j<12;++j) acc[i][j] += av[i]*bv[j];
    }
    __syncthreads();
  }
  int jc = tx*4;
  float4 bb0 = *(const float4*)&dbhh[jc];
  float4 bb1 = *(const float4*)&dbhh[jc+128];
  float4 bb2 = *(const float4*)&dbhh[jc+256];
  float4 w00 = *(const float4*)&w0[jc];
  float4 w01 = *(const float4*)&w0[jc+128];
  float4 w02 = *(const float4*)&w0[jc+256];
  float4 owv = *(const float4*)&ow[jc];
  float psum[8];
  #pragma unroll
  for (int rr=0;rr<8;++rr){
    int row = m0 + ty*8 + rr;
    float p = pred[row];
    const float* gx = ctxGX + (size_t)row*384 + jc;
    float4 g0 = *(const float4*)gx;
    float4 g1 = *(const float4*)(gx+128);
    float4 g2 = *(const float4*)(gx+256);
    float4 hv = *(float4*)&h[(size_t)row*NH + jc];
    float4 hn;
    float r_, z_, n_;
    r_ = sigf(g0.x + p*w00.x + acc[rr][0] + bb0.x); z_ = sigf(g1.x + p*w01.x + acc[rr][4] + bb1.x);
    n_ = tanhf(g2.x + p*w02.x + r_*(acc[rr][8] + bb2.x));  hn.x = (1.f-z_)*n_ + z_*hv.x;
    r_ = sigf(g0.y + p*w00.y + acc[rr][1] + bb0.y); z_ = sigf(g1.y + p*w01.y + acc[rr][5] + bb1.y);
    n_ = tanhf(g2.y + p*w02.y + r_*(acc[rr][9] + bb2.y));  hn.y = (1.f-z_)*n_ + z_*hv.y;
    r_ = sigf(g0.z + p*w00.z + acc[rr][2] + bb0.z); z_ = sigf(g1.z + p*w01.z + acc[rr][6] + bb1.z);
    n_ = tanhf(g2.z + p*w02.z + r_*(acc[rr][10] + bb2.z)); hn.z = (1.f-z_)*n_ + z_*hv.z;
    r_ = sigf(g0.w + p*w00.w + acc[rr][3] + bb0.w); z_ = sigf(g1.w + p*w01.w + acc[rr][7] + bb1.w);
    n_ = tanhf(g2.w + p*w02.w + r_*(acc[rr][11] + bb2.w)); hn.w = (1.f-z_)*n_ + z_*hv.w;
    *(float4*)&h[(size_t)row*NH + jc] = hn;
    psum[rr] = hn.x*owv.x + hn.y*owv.y + hn.z*owv.z + hn.w*owv.w;
  }
  #pragma unroll
  for (int off=16; off; off>>=1){
    #pragma unroll
    for (int rr=0;rr<8;++rr) psum[rr] += __shfl_xor(psum[rr], off, 64);
  }
  if (tx == 0){
    #pragma unroll
    for (int rr=0;rr<8;++rr){
      int row = m0 + ty*8 + rr;
      float pn = psum[rr] + ob[0];
      pred[row] = pn;
      preds_out[row] = pn;
    }
  }
}

// fusion, attn gate, write z in (tau, i, ZSTR) layout + ctx + pred0
__global__ __launch_bounds__(256) void k_zbuild(const float* __restrict__ x,
    const float* __restrict__ S, const float* __restrict__ cw, const float* __restrict__ cb,
    const float* __restrict__ aw, const float* __restrict__ ab,
    float* __restrict__ ztm, float* __restrict__ ctx, float* __restrict__ pred0){
  int tid = threadIdx.x;
  int rl = tid >> 6, l = tid & 63;
  int r = blockIdx.x*4 + rl;
  int n = r % NNODE, bt = r / NNODE, t = bt % NT, b = bt / NT;
  const float* xr = x + (size_t)r*NF;
  float fu, fu64 = 0.f;
  if (l == 0){
    fu = xr[0];
    float s_ = cb[31];
    #pragma unroll
    for (int f=0; f<13; ++f) s_ += xr[1+f]*cw[31*13+f];
    fu64 = s_ > 0.f ? s_ : 0.f;
  } else if (l < 33){
    fu = S[(size_t)(b*NNODE+n)*G3 + t*32 + (l-1)];
  } else {
    int o = l - 33;
    float s_ = cb[o];
    #pragma unroll
    for (int f=0; f<13; ++f) s_ += xr[1+f]*cw[o*13+f];
    fu = s_ > 0.f ? s_ : 0.f;
  }
  float part = fu*aw[l] + (l==0 ? fu64*aw[64] : 0.f);
  #pragma unroll
  for (int off=32; off; off>>=1) part += __shfl_down(part, off, 64);
  part = __shfl(part, 0, 64);
  float attn = sigf(part + ab[0]);
  int i_ = r / NT, tau = r % NT;          // scrambled reshape (B*N, T, 65)
  float* zr = ztm + ((size_t)tau*ROWS + i_)*ZSTR;
  zr[l] = fu*attn;
  if (l == 0) zr[64] = fu64*attn;         // pad cols 65..79 multiply zero weights
  if (t == NT-1){
    if (l >= 33) ctx[(size_t)(b*NNODE+n)*32 + (l-33)] = fu;
    if (l == 0){ ctx[(size_t)(b*NNODE+n)*32 + 31] = fu64; pred0[b*NNODE+n] = xr[0]; }
  }
}

__global__ __launch_bounds__(256) void k_out(const float* __restrict__ preds, float* __restrict__ out){
  int idx = blockIdx.x*256 + threadIdx.x;
  if (idx >= NT*ROWS) return;
  int n = idx % NNODE;
  int t2 = idx / NNODE;
  int hor = t2 % NT;
  int b = t2 / NT;
  out[idx] = preds[(size_t)hor*ROWS + b*NNODE + n];
}

extern "C" void kernel_launch(void* const* d_in, const int* in_sizes, int n_in,
                              void* d_out, int out_size, void* d_ws, size_t ws_size,
                              hipStream_t stream){
  const float* x     = (const float*)d_in[0];
  const float* Aph   = (const float*)d_in[1];
  const float* fcw   = (const float*)d_in[2];
  const float* fcb   = (const float*)d_in[3];
  const float* alp   = (const float*)d_in[4];
  const float* cw    = (const float*)d_in[5];
  const float* cb    = (const float*)d_in[6];
  const float* tw    = (const float*)d_in[7];
  const float* tb    = (const float*)d_in[8];
  const float* theta = (const float*)d_in[9];
  const float* aw    = (const float*)d_in[10];
  const float* ab    = (const float*)d_in[11];
  const float* ewih  = (const float*)d_in[12];
  const float* ewhh  = (const float*)d_in[13];
  const float* ebih  = (const float*)d_in[14];
  const float* ebhh  = (const float*)d_in[15];
  const float* dwih  = (const float*)d_in[16];
  const float* dwhh  = (const float*)d_in[17];
  const float* dbih  = (const float*)d_in[18];
  const float* dbhh  = (const float*)d_in[19];
  const float* ow    = (const float*)d_in[20];
  const float* ob    = (const float*)d_in[21];
  float* out = (float*)d_out;

  const size_t SZ_H    = (size_t)ROWS*NH;
  const size_t SZ_CTX  = (size_t)ROWS*32;
  const size_t SZ_PRED = (size_t)ROWS;
  const size_t SZ_PREDS= (size_t)NT*ROWS;
  const size_t SZ_G    = (size_t)ROWS*G3;
  const size_t SZ_ABUF = (size_t)NB*NNODE*LSTR;
  const size_t SZ_EMB  = (size_t)ROWS*16;
  const size_t SZ_Z    = (size_t)NT*ROWS*ZSTR;   // 25.4M >= 2*SZ_G

  float* w = (float*)d_ws;
  size_t off = 0;
  auto alloc = [&](size_t nfl){ float* p = w + off; off += nfl; return p; };
  float* h     = alloc(SZ_H);
  float* ctx   = alloc(SZ_CTX);
  float* pred  = alloc(SZ_PRED);
  float* preds = alloc(SZ_PREDS);
  float* Abuf  = alloc(SZ_ABUF);
  float* emb   = alloc(SZ_EMB);
  float* rsum  = alloc(SZ_PRED);
  float* lam   = alloc((size_t)NB);
  float* wt    = alloc((size_t)WT_TOTAL);
  float* Sslot = alloc(SZ_G);      // t_feat -> S -> ctxGX
  float* Zzone = alloc(SZ_Z);      // P1 | P2 ; later z (tau,i,ZSTR)
  float* P1 = Zzone;
  float* P2 = Zzone + SZ_G;
  (void)n_in; (void)in_sizes;

  if (ws_size < off*sizeof(float)){    // tripwire: workspace too small
    k_sentinel<<<(out_size+255)/256, 256, 0, stream>>>(out, out_size);
    return;
  }

  float* WENC  = wt + OFF_WENC;
  float* dwhhT = wt + OFF_DWHHT;
  float* dwihT = wt + OFF_DWIHT;
  float* w0    = wt + OFF_W0;

  k_prep<<<(WT_TOTAL+255)/256, 256, 0, stream>>>(ewih, ewhh, dwih, dwhh, wt);
  float* tfeat = Sslot;
  k_emb<<<(ROWS*16)/256, 256, 0, stream>>>(x, fcw, fcb, emb);
  k_adj<<<ROWS/4, 256, 0, stream>>>(emb, Aph, alp, Abuf, rsum);
  k_lam<<<NB, 256, 0, stream>>>(rsum, lam);
  k_lap<<<(NB*NNODE*LSTR)/256, 256, 0, stream>>>(Abuf, lam);
  k_tcn<<<(BTN*32)/256, 256, 0, stream>>>(x, tw, tb, tfeat);
  k_thetaBC<<<BTN/8, 256, 0, stream>>>(tfeat, theta, P2, P1);
  // P2 <- 2*(L @ P1) + P2
  gemm128<<<dim3(3, 2, NB), 256, 0, stream>>>(Abuf, LSTR, (long long)NNODE*LSTR,
      P1, (long long)NNODE*G3, nullptr,
      P2, (long long)NNODE*G3, 2.f, 1.f, 0,
      P2, (long long)NNODE*G3, NNODE, 13);
  k_thetaA<<<BTN/8, 256, 0, stream>>>(tfeat, theta, P1);
  // Sslot <- relu((L @ P2) + P1)
  gemm128<<<dim3(3, 2, NB), 256, 0, stream>>>(Abuf, LSTR, (long long)NNODE*LSTR,
      P2, (long long)NNODE*G3, nullptr,
      P1, (long long)NNODE*G3, 1.f, 1.f, 1,
      Sslot, (long long)NNODE*G3, NNODE, 13);
  k_zbuild<<<BTN/4, 256, 0, stream>>>(x, Sslot, cw, cb, aw, ab, Zzone, ctx, pred);
  hipMemsetAsync(h, 0, SZ_H*sizeof(float), stream);

  for (int t=0; t<NT; ++t){
    k_enc_fused2<<<ROWS/64, 256, 0, stream>>>(h, Zzone + (size_t)t*ROWS*ZSTR,
        WENC, ebih, ebhh);
  }
  float* ctxGX = Sslot;  // S dead after zbuild
  gemm128<<<dim3(3, ROWS/128, 1), 256, 0, stream>>>(
      ctx, 32, 0, dwihT, 0, dbih,
      nullptr, 0, 1.f, 0.f, 0, ctxGX, 0, ROWS, 2);
  for (int s=0; s<NT; ++s){
    k_dec_fused2<<<ROWS/64, 256, 0, stream>>>(h, dwhhT, dbhh, ctxGX, w0, ow, ob,
        pred, preds + (size_t)s*ROWS);
  }
  k_out<<<(NT*ROWS)/256, 256, 0, stream>>>(preds, out);
}

// Round 6
// 2301.107 us; speedup vs baseline: 1.1112x; 1.1112x over previous
//
#include <hip/hip_runtime.h>
#include <math.h>

#define NB 128      // B
#define NT 12       // T
#define NNODE 207   // N
#define NF 14       // F
#define NH 128      // H
#define ROWS (NB*NNODE)      // 26496
#define BTN (NB*NT*NNODE)    // 317952
#define G3 (3*NH)            // 384
#define LSTR 208             // padded Laplacian row stride
#define ZSTR 80              // padded z row stride (65 -> 80, 5 chunks of 16)

__device__ __forceinline__ float sigf(float x){ return 1.0f/(1.0f+__expf(-x)); }

__global__ __launch_bounds__(256) void k_sentinel(float* __restrict__ out, int n){
  int i = blockIdx.x*256 + threadIdx.x;
  if (i < n) out[i] = 12345.0f;
}

// packed transposed weights:
// WENC: 208x384 (rows 0..64 = ewih^T, 65..79 = 0, 80..207 = ewhh^T)
// DWHHT: 128x384 ; DWIHT: 32x384 (dwih cols 1..32) ; W0: 384 (dwih col 0)
#define OFF_WENC  0
#define OFF_DWHHT (208*384)
#define OFF_DWIHT (208*384 + 128*384)
#define OFF_W0    (208*384 + 128*384 + 32*384)
#define WT_TOTAL  (208*384 + 128*384 + 32*384 + 384)
__global__ __launch_bounds__(256) void k_prep(const float* __restrict__ ewih,
    const float* __restrict__ ewhh, const float* __restrict__ dwih,
    const float* __restrict__ dwhh, float* __restrict__ wt){
  int i = blockIdx.x*256 + threadIdx.x;
  if (i < OFF_DWHHT){
    int k = i/384, n = i%384;
    wt[i] = (k < 65) ? ewih[n*65 + k] : (k < 80 ? 0.f : ewhh[n*128 + (k-80)]);
  } else if (i < OFF_DWIHT){
    int j = i - OFF_DWHHT; int k = j/384, n = j%384;
    wt[i] = dwhh[n*128 + k];
  } else if (i < OFF_W0){
    int j = i - OFF_DWIHT; int k = j/384, n = j%384;
    wt[i] = dwih[n*33 + 1 + k];
  } else if (i < WT_TOTAL){
    int n = i - OFF_W0;
    wt[i] = dwih[n*33];
  }
}

// emb = tanh(state * fc_w + fc_b)   (B,N,16)
__global__ __launch_bounds__(256) void k_emb(const float* __restrict__ x,
    const float* __restrict__ w, const float* __restrict__ b, float* __restrict__ emb){
  int idx = blockIdx.x*256 + threadIdx.x;
  if (idx >= ROWS*16) return;
  int j = idx & 15, row = idx >> 4;
  int bb = row / NNODE, n = row % NNODE;
  float s = x[((bb*NT + (NT-1))*NNODE + n)*NF];
  emb[idx] = tanhf(s*w[j] + b[j]);
}

// wave-per-row: A_dyn row, top-10 (tie->lowest idx), sparse softmax, blend, rowsum
__global__ __launch_bounds__(256) void k_adj(const float* __restrict__ emb,
    const float* __restrict__ Aph, const float* __restrict__ alp,
    float* __restrict__ Abuf, float* __restrict__ rsum){
  int wid = threadIdx.x >> 6, lane = threadIdx.x & 63;
  int row = blockIdx.x*4 + wid;
  int bb = row / NNODE, n = row % NNODE;
  const float4* er = (const float4*)(emb + (size_t)row*16);
  float4 e0 = er[0], e1 = er[1], e2 = er[2], e3 = er[3];
  float d[4];
  #pragma unroll
  for (int q=0;q<4;++q){
    int m = lane + q*64;
    float dd = -1.f;
    if (m < NNODE){
      const float4* em = (const float4*)(emb + (size_t)(bb*NNODE+m)*16);
      float4 m0 = em[0], m1 = em[1], m2 = em[2], m3 = em[3];
      dd = e0.x*m0.x + e0.y*m0.y + e0.z*m0.z + e0.w*m0.w
         + e1.x*m1.x + e1.y*m1.y + e1.z*m1.z + e1.w*m1.w
         + e2.x*m2.x + e2.y*m2.y + e2.z*m2.z + e2.w*m2.w
         + e3.x*m3.x + e3.y*m3.y + e3.z*m3.z + e3.w*m3.w;
      dd = dd > 0.f ? dd : 0.f;
    }
    d[q] = dd;
  }
  int km = 0;
  float vmax = 0.f;
  for (int it=0; it<10; ++it){
    float v = -1.f; int mi = 1<<20;
    #pragma unroll
    for (int q=0;q<4;++q){
      if (d[q] >= 0.f && !((km>>q)&1) && d[q] > v){ v = d[q]; mi = lane + q*64; }
    }
    #pragma unroll
    for (int off=1; off<64; off<<=1){
      float v2 = __shfl_xor(v, off, 64);
      int  i2 = __shfl_xor(mi, off, 64);
      if (v2 > v || (v2 == v && i2 < mi)){ v = v2; mi = i2; }
    }
    if (it == 0) vmax = v;
    if ((mi & 63) == lane) km |= 1 << (mi >> 6);
  }
  float a = sigf(alp[0]);
  float eneg = __expf(-vmax);
  float p[4]; float ps = 0.f;
  #pragma unroll
  for (int q=0;q<4;++q){
    p[q] = 0.f;
    if (d[q] >= 0.f) p[q] = ((km>>q)&1) ? __expf(d[q]-vmax) : eneg;
    ps += p[q];
  }
  #pragma unroll
  for (int off=1; off<64; off<<=1) ps += __shfl_xor(ps, off, 64);
  float inv = (1.f - a)/ps;
  float rs = 0.f;
  #pragma unroll
  for (int q=0;q<4;++q){
    int m = lane + q*64;
    if (m < NNODE){
      float Av = a*Aph[n*NNODE + m] + p[q]*inv;
      Abuf[(size_t)row*LSTR + m] = Av;
      rs += Av;
    }
  }
  if (lane == 0) Abuf[(size_t)row*LSTR + 207] = 0.f;   // pad col
  #pragma unroll
  for (int off=1; off<64; off<<=1) rs += __shfl_xor(rs, off, 64);
  if (lane == 0) rsum[row] = rs;
}

__global__ __launch_bounds__(256) void k_lam(const float* __restrict__ rsum, float* __restrict__ lam){
  __shared__ float rv[256];
  int b = blockIdx.x, tid = threadIdx.x;
  rv[tid] = (tid < NNODE) ? rsum[b*NNODE+tid] : -1e30f;
  __syncthreads();
  for (int s=128;s>0;s>>=1){ if (tid<s) rv[tid]=fmaxf(rv[tid],rv[tid+s]); __syncthreads(); }
  if (tid==0) lam[b] = fmaxf(rv[0], 1.0f);
}

__global__ __launch_bounds__(256) void k_lap(float* __restrict__ Abuf, const float* __restrict__ lam){
  int idx = blockIdx.x*256 + threadIdx.x;
  if (idx >= NB*NNODE*LSTR) return;
  int b = idx / (NNODE*LSTR);
  int rem = idx % (NNODE*LSTR);
  int n = rem / LSTR, m = rem % LSTR;
  Abuf[idx] = 2.f*Abuf[idx]/lam[b] - (n==m ? 1.f : 0.f);   // m==207: 0 stays 0
}

// causal conv(3) + GLU -> t_feat (B,T,N,32)
__global__ __launch_bounds__(256) void k_tcn(const float* __restrict__ x,
    const float* __restrict__ w, const float* __restrict__ bcn, float* __restrict__ tfeat){
  int idx = blockIdx.x*256 + threadIdx.x;
  if (idx >= BTN*32) return;
  int o = idx & 31; int r = idx >> 5;
  int n = r % NNODE, bt = r / NNODE, t = bt % NT, b = bt / NT;
  float t0 = (t>=2)? x[((size_t)(b*NT+t-2)*NNODE+n)*NF] : 0.f;
  float t1 = (t>=1)? x[((size_t)(b*NT+t-1)*NNODE+n)*NF] : 0.f;
  float t2 = x[((size_t)(b*NT+t)*NNODE+n)*NF];
  float P = bcn[o]    + w[o*3]*t0       + w[o*3+1]*t1       + w[o*3+2]*t2;
  float Q = bcn[o+32] + w[(o+32)*3]*t0  + w[(o+32)*3+1]*t1  + w[(o+32)*3+2]*t2;
  tfeat[(size_t)r*32 + o] = P * sigf(Q);
}

// RB = tfeat@th1 -> P2 ; RC = tfeat@th2 -> P1     layout (B, N, T*32)
__global__ __launch_bounds__(256) void k_thetaBC(const float* __restrict__ tfeat,
    const float* __restrict__ theta, float* __restrict__ P2, float* __restrict__ P1){
  __shared__ float thB[32][33], thC[32][33];
  __shared__ float tf[8][32];
  int tid = threadIdx.x;
  for (int i=tid; i<1024; i+=256){
    int f = i >> 5, o = i & 31;
    thB[o][f] = theta[1024+f*32+o]; thC[o][f] = theta[2048+f*32+o];
  }
  int rl = tid >> 5, o = tid & 31;
  int r = blockIdx.x*8 + rl;
  tf[rl][o] = tfeat[(size_t)r*32 + o];
  __syncthreads();
  float aB=0.f, aC=0.f;
  #pragma unroll
  for (int f=0; f<32; ++f){
    float t = tf[rl][f];
    aB += t*thB[o][f]; aC += t*thC[o][f];
  }
  int n = r % NNODE, bt = r / NNODE, t = bt % NT, b = bt / NT;
  size_t outi = (size_t)(b*NNODE+n)*G3 + t*32 + o;
  P2[outi]=aB; P1[outi]=aC;
}

// RA = tfeat@(th0-th2) -> P1
__global__ __launch_bounds__(256) void k_thetaA(const float* __restrict__ tfeat,
    const float* __restrict__ theta, float* __restrict__ P1){
  __shared__ float thA[32][33];
  __shared__ float tf[8][32];
  int tid = threadIdx.x;
  for (int i=tid; i<1024; i+=256){
    int f = i >> 5, o = i & 31;
    thA[o][f] = theta[f*32+o] - theta[2048+f*32+o];
  }
  int rl = tid >> 5, o = tid & 31;
  int r = blockIdx.x*8 + rl;
  tf[rl][o] = tfeat[(size_t)r*32 + o];
  __syncthreads();
  float aA=0.f;
  #pragma unroll
  for (int f=0; f<32; ++f) aA += tf[rl][f]*thA[o][f];
  int n = r % NNODE, bt = r / NNODE, t = bt % NT, b = bt / NT;
  P1[(size_t)(b*NNODE+n)*G3 + t*32 + o] = aA;
}

// ---- unified 128x128 GEMM: C = [alpha*](A @ B) + bias|beta*Y [relu]
__global__ __launch_bounds__(256) void gemm128(
    const float* __restrict__ Ab, int lda, long long sA,
    const float* __restrict__ Bb, long long sB,
    const float* __restrict__ bias,
    const float* __restrict__ Yb, long long sY, float alphaV, float betaV, int do_relu,
    float* __restrict__ Cb, long long sC, int M, int kchunks){
  __shared__ float As[16][132];
  __shared__ float Bs[16][132];
  int bz = blockIdx.z;
  const float* A = Ab + (size_t)bz*sA;
  const float* B = Bb + (size_t)bz*sB;
  float* C = Cb + (size_t)bz*sC;
  int n0 = blockIdx.x*128, m0 = blockIdx.y*128;
  int tid = threadIdx.x, tx = tid & 15, ty = tid >> 4;
  float acc[8][8] = {};
  int ar = tid & 127, ak = (tid >> 7)*8;
  int bk = tid >> 4, bn = (tid & 15)*8;
  for (int kc=0; kc<kchunks; ++kc){
    int k0 = kc*16;
    int m = m0 + ar;
    if (m < M){
      const float* ap = A + (size_t)m*lda + k0 + ak;
      float4 v0 = *(const float4*)ap, v1 = *(const float4*)(ap+4);
      As[ak+0][ar]=v0.x; As[ak+1][ar]=v0.y; As[ak+2][ar]=v0.z; As[ak+3][ar]=v0.w;
      As[ak+4][ar]=v1.x; As[ak+5][ar]=v1.y; As[ak+6][ar]=v1.z; As[ak+7][ar]=v1.w;
    } else {
      #pragma unroll
      for (int j=0;j<8;++j) As[ak+j][ar]=0.f;
    }
    const float* bp = B + (size_t)(k0+bk)*384 + n0 + bn;
    float4 w0_ = *(const float4*)bp, w1_ = *(const float4*)(bp+4);
    *(float4*)&Bs[bk][bn] = w0_; *(float4*)&Bs[bk][bn+4] = w1_;
    __syncthreads();
    #pragma unroll
    for (int kk=0;kk<16;++kk){
      float4 a0 = *(const float4*)&As[kk][ty*8];
      float4 a1 = *(const float4*)&As[kk][ty*8+4];
      float4 b0 = *(const float4*)&Bs[kk][tx*4];
      float4 b1 = *(const float4*)&Bs[kk][64+tx*4];
      float av[8] = {a0.x,a0.y,a0.z,a0.w,a1.x,a1.y,a1.z,a1.w};
      float bv[8] = {b0.x,b0.y,b0.z,b0.w,b1.x,b1.y,b1.z,b1.w};
      #pragma unroll
      for (int i=0;i<8;++i)
        #pragma unroll
        for (int j=0;j<8;++j) acc[i][j] += av[i]*bv[j];
    }
    __syncthreads();
  }
  if (bias){
    float bl[4], bh_[4];
    #pragma unroll
    for (int j=0;j<4;++j){ bl[j]=bias[n0+tx*4+j]; bh_[j]=bias[n0+64+tx*4+j]; }
    #pragma unroll
    for (int i=0;i<8;++i){
      int m2 = m0 + ty*8 + i; if (m2 >= M) continue;
      float4 s0, s1;
      s0.x=acc[i][0]+bl[0]; s0.y=acc[i][1]+bl[1]; s0.z=acc[i][2]+bl[2]; s0.w=acc[i][3]+bl[3];
      s1.x=acc[i][4]+bh_[0]; s1.y=acc[i][5]+bh_[1]; s1.z=acc[i][6]+bh_[2]; s1.w=acc[i][7]+bh_[3];
      *(float4*)&C[(size_t)m2*384 + n0 + tx*4] = s0;
      *(float4*)&C[(size_t)m2*384 + n0 + 64 + tx*4] = s1;
    }
  } else {
    const float* Y = Yb + (size_t)bz*sY;
    #pragma unroll
    for (int i=0;i<8;++i){
      int m2 = m0 + ty*8 + i; if (m2 >= M) continue;
      const float* yr = Y + (size_t)m2*384;
      float* cr = C + (size_t)m2*384;
      float4 y0 = *(const float4*)(yr + n0 + tx*4);
      float4 y1 = *(const float4*)(yr + n0 + 64 + tx*4);
      float4 s0, s1;
      s0.x = alphaV*acc[i][0] + betaV*y0.x; s0.y = alphaV*acc[i][1] + betaV*y0.y;
      s0.z = alphaV*acc[i][2] + betaV*y0.z; s0.w = alphaV*acc[i][3] + betaV*y0.w;
      s1.x = alphaV*acc[i][4] + betaV*y1.x; s1.y = alphaV*acc[i][5] + betaV*y1.y;
      s1.z = alphaV*acc[i][6] + betaV*y1.z; s1.w = alphaV*acc[i][7] + betaV*y1.w;
      if (do_relu){
        s0.x=fmaxf(s0.x,0.f); s0.y=fmaxf(s0.y,0.f); s0.z=fmaxf(s0.z,0.f); s0.w=fmaxf(s0.w,0.f);
        s1.x=fmaxf(s1.x,0.f); s1.y=fmaxf(s1.y,0.f); s1.z=fmaxf(s1.z,0.f); s1.w=fmaxf(s1.w,0.f);
      }
      *(float4*)(cr + n0 + tx*4) = s0;
      *(float4*)(cr + n0 + 64 + tx*4) = s1;
    }
  }
}

// ---- fully-fused encoder step: h' = GRU(z_t@wih^T+bih, h@whh^T+bhh, h)
// 64 rows x 384 cols, 512 threads, acc 4x12 + accN 4x4 (low VGPR -> occupancy)
// WENC rows 0..79 = wih^T (65..79 zero), rows 80..207 = whh^T
__global__ __launch_bounds__(512) void k_enc_fused2(float* __restrict__ h,
    const float* __restrict__ zt, const float* __restrict__ WENC,
    const float* __restrict__ bih, const float* __restrict__ bhh){
  __shared__ float As[16][68];
  __shared__ float Bs[16][388];
  int m0 = blockIdx.x*64;
  int tid = threadIdx.x, tx = tid & 31, ty = tid >> 5;
  float acc[4][12] = {};
  float accN[4][4] = {};
  for (int kc=0; kc<13; ++kc){
    int k0 = kc*16;
    if (tid < 256){
      int r = tid & 63, kq = (tid >> 6)*4;
      const float* ap = (kc < 5)
        ? zt + (size_t)(m0+r)*ZSTR + k0 + kq
        : h  + (size_t)(m0+r)*NH + (k0-80) + kq;
      float4 v = *(const float4*)ap;
      As[kq+0][r]=v.x; As[kq+1][r]=v.y; As[kq+2][r]=v.z; As[kq+3][r]=v.w;
    }
    {
      int kr = tid >> 5, cb = (tid & 31)*4;
      const float* bp = &WENC[(size_t)(k0+kr)*384 + cb];
      *(float4*)&Bs[kr][cb]     = *(const float4*)(bp);
      *(float4*)&Bs[kr][cb+128] = *(const float4*)(bp+128);
      *(float4*)&Bs[kr][cb+256] = *(const float4*)(bp+256);
    }
    __syncthreads();
    if (kc < 5){
      #pragma unroll
      for (int kk=0;kk<16;++kk){
        float4 a = *(const float4*)&As[kk][ty*4];
        float4 b0 = *(const float4*)&Bs[kk][tx*4];
        float4 b1 = *(const float4*)&Bs[kk][tx*4+128];
        float4 b2 = *(const float4*)&Bs[kk][tx*4+256];
        float av[4] = {a.x,a.y,a.z,a.w};
        float bv[12] = {b0.x,b0.y,b0.z,b0.w,b1.x,b1.y,b1.z,b1.w,b2.x,b2.y,b2.z,b2.w};
        #pragma unroll
        for (int i=0;i<4;++i)
          #pragma unroll
          for (int j=0;j<12;++j) acc[i][j] += av[i]*bv[j];
      }
    } else {
      #pragma unroll
      for (int kk=0;kk<16;++kk){
        float4 a = *(const float4*)&As[kk][ty*4];
        float4 b0 = *(const float4*)&Bs[kk][tx*4];
        float4 b1 = *(const float4*)&Bs[kk][tx*4+128];
        float4 b2 = *(const float4*)&Bs[kk][tx*4+256];
        float av[4] = {a.x,a.y,a.z,a.w};
        float bv[8] = {b0.x,b0.y,b0.z,b0.w,b1.x,b1.y,b1.z,b1.w};
        float nv[4] = {b2.x,b2.y,b2.z,b2.w};
        #pragma unroll
        for (int i=0;i<4;++i){
          #pragma unroll
          for (int j=0;j<8;++j) acc[i][j] += av[i]*bv[j];
          #pragma unroll
          for (int j=0;j<4;++j) accN[i][j] += av[i]*nv[j];
        }
      }
    }
    __syncthreads();
  }
  int jc = tx*4;
  float4 bir = *(const float4*)&bih[jc];
  float4 biz = *(const float4*)&bih[jc+128];
  float4 bin = *(const float4*)&bih[jc+256];
  float4 bhr = *(const float4*)&bhh[jc];
  float4 bhz = *(const float4*)&bhh[jc+128];
  float4 bhn = *(const float4*)&bhh[jc+256];
  #pragma unroll
  for (int rr=0;rr<4;++rr){
    int row = m0 + ty*4 + rr;
    float4 hv = *(float4*)&h[(size_t)row*NH + jc];
    float r_, z_, n_;
    r_ = sigf(acc[rr][0] + bir.x + bhr.x); z_ = sigf(acc[rr][4] + biz.x + bhz.x);
    n_ = tanhf(acc[rr][8]  + bin.x + r_*(accN[rr][0] + bhn.x)); hv.x = (1.f-z_)*n_ + z_*hv.x;
    r_ = sigf(acc[rr][1] + bir.y + bhr.y); z_ = sigf(acc[rr][5] + biz.y + bhz.y);
    n_ = tanhf(acc[rr][9]  + bin.y + r_*(accN[rr][1] + bhn.y)); hv.y = (1.f-z_)*n_ + z_*hv.y;
    r_ = sigf(acc[rr][2] + bir.z + bhr.z); z_ = sigf(acc[rr][6] + biz.z + bhz.z);
    n_ = tanhf(acc[rr][10] + bin.z + r_*(accN[rr][2] + bhn.z)); hv.z = (1.f-z_)*n_ + z_*hv.z;
    r_ = sigf(acc[rr][3] + bir.w + bhr.w); z_ = sigf(acc[rr][7] + biz.w + bhz.w);
    n_ = tanhf(acc[rr][11] + bin.w + r_*(accN[rr][3] + bhn.w)); hv.w = (1.f-z_)*n_ + z_*hv.w;
    *(float4*)&h[(size_t)row*NH + jc] = hv;
  }
}

// ---- fused decoder step: gh GEMM (K=128) + GRU + out-dot, pred chain
// 64 rows x 384 cols, 512 threads, acc 4x12
__global__ __launch_bounds__(512) void k_dec_fused2(float* __restrict__ h,
    const float* __restrict__ BT, const float* __restrict__ dbhh,
    const float* __restrict__ ctxGX, const float* __restrict__ w0,
    const float* __restrict__ ow, const float* __restrict__ ob,
    float* __restrict__ pred, float* __restrict__ preds_out){
  __shared__ float As[16][68];
  __shared__ float Bs[16][388];
  int m0 = blockIdx.x*64;
  int tid = threadIdx.x, tx = tid & 31, ty = tid >> 5;
  float acc[4][12] = {};
  for (int kc=0; kc<8; ++kc){
    int k0 = kc*16;
    if (tid < 256){
      int r = tid & 63, kq = (tid >> 6)*4;
      float4 v = *(const float4*)&h[(size_t)(m0+r)*NH + k0 + kq];
      As[kq+0][r]=v.x; As[kq+1][r]=v.y; As[kq+2][r]=v.z; As[kq+3][r]=v.w;
    }
    {
      int kr = tid >> 5, cb = (tid & 31)*4;
      const float* bp = &BT[(size_t)(k0+kr)*384 + cb];
      *(float4*)&Bs[kr][cb]     = *(const float4*)(bp);
      *(float4*)&Bs[kr][cb+128] = *(const float4*)(bp+128);
      *(float4*)&Bs[kr][cb+256] = *(const float4*)(bp+256);
    }
    __syncthreads();
    #pragma unroll
    for (int kk=0;kk<16;++kk){
      float4 a = *(const float4*)&As[kk][ty*4];
      float4 b0 = *(const float4*)&Bs[kk][tx*4];
      float4 b1 = *(const float4*)&Bs[kk][tx*4+128];
      float4 b2 = *(const float4*)&Bs[kk][tx*4+256];
      float av[4] = {a.x,a.y,a.z,a.w};
      float bv[12] = {b0.x,b0.y,b0.z,b0.w,b1.x,b1.y,b1.z,b1.w,b2.x,b2.y,b2.z,b2.w};
      #pragma unroll
      for (int i=0;i<4;++i)
        #pragma unroll
        for (int j=0;j<12;++j) acc[i][j] += av[i]*bv[j];
    }
    __syncthreads();
  }
  int jc = tx*4;
  float4 bb0 = *(const float4*)&dbhh[jc];
  float4 bb1 = *(const float4*)&dbhh[jc+128];
  float4 bb2 = *(const float4*)&dbhh[jc+256];
  float4 w00 = *(const float4*)&w0[jc];
  float4 w01 = *(const float4*)&w0[jc+128];
  float4 w02 = *(const float4*)&w0[jc+256];
  float4 owv = *(const float4*)&ow[jc];
  float psum[4];
  #pragma unroll
  for (int rr=0;rr<4;++rr){
    int row = m0 + ty*4 + rr;
    float p = pred[row];
    const float* gx = ctxGX + (size_t)row*384 + jc;
    float4 g0 = *(const float4*)gx;
    float4 g1 = *(const float4*)(gx+128);
    float4 g2 = *(const float4*)(gx+256);
    float4 hv = *(float4*)&h[(size_t)row*NH + jc];
    float4 hn;
    float r_, z_, n_;
    r_ = sigf(g0.x + p*w00.x + acc[rr][0] + bb0.x); z_ = sigf(g1.x + p*w01.x + acc[rr][4] + bb1.x);
    n_ = tanhf(g2.x + p*w02.x + r_*(acc[rr][8] + bb2.x));  hn.x = (1.f-z_)*n_ + z_*hv.x;
    r_ = sigf(g0.y + p*w00.y + acc[rr][1] + bb0.y); z_ = sigf(g1.y + p*w01.y + acc[rr][5] + bb1.y);
    n_ = tanhf(g2.y + p*w02.y + r_*(acc[rr][9] + bb2.y));  hn.y = (1.f-z_)*n_ + z_*hv.y;
    r_ = sigf(g0.z + p*w00.z + acc[rr][2] + bb0.z); z_ = sigf(g1.z + p*w01.z + acc[rr][6] + bb1.z);
    n_ = tanhf(g2.z + p*w02.z + r_*(acc[rr][10] + bb2.z)); hn.z = (1.f-z_)*n_ + z_*hv.z;
    r_ = sigf(g0.w + p*w00.w + acc[rr][3] + bb0.w); z_ = sigf(g1.w + p*w01.w + acc[rr][7] + bb1.w);
    n_ = tanhf(g2.w + p*w02.w + r_*(acc[rr][11] + bb2.w)); hn.w = (1.f-z_)*n_ + z_*hv.w;
    *(float4*)&h[(size_t)row*NH + jc] = hn;
    psum[rr] = hn.x*owv.x + hn.y*owv.y + hn.z*owv.z + hn.w*owv.w;
  }
  #pragma unroll
  for (int off=16; off; off>>=1){
    #pragma unroll
    for (int rr=0;rr<4;++rr) psum[rr] += __shfl_xor(psum[rr], off, 64);
  }
  if (tx == 0){
    #pragma unroll
    for (int rr=0;rr<4;++rr){
      int row = m0 + ty*4 + rr;
      float pn = psum[rr] + ob[0];
      pred[row] = pn;
      preds_out[row] = pn;
    }
  }
}

// fusion, attn gate, write z in (tau, i, ZSTR) layout + ctx + pred0
__global__ __launch_bounds__(256) void k_zbuild(const float* __restrict__ x,
    const float* __restrict__ S, const float* __restrict__ cw, const float* __restrict__ cb,
    const float* __restrict__ aw, const float* __restrict__ ab,
    float* __restrict__ ztm, float* __restrict__ ctx, float* __restrict__ pred0){
  int tid = threadIdx.x;
  int rl = tid >> 6, l = tid & 63;
  int r = blockIdx.x*4 + rl;
  int n = r % NNODE, bt = r / NNODE, t = bt % NT, b = bt / NT;
  const float* xr = x + (size_t)r*NF;
  float fu, fu64 = 0.f;
  if (l == 0){
    fu = xr[0];
    float s_ = cb[31];
    #pragma unroll
    for (int f=0; f<13; ++f) s_ += xr[1+f]*cw[31*13+f];
    fu64 = s_ > 0.f ? s_ : 0.f;
  } else if (l < 33){
    fu = S[(size_t)(b*NNODE+n)*G3 + t*32 + (l-1)];
  } else {
    int o = l - 33;
    float s_ = cb[o];
    #pragma unroll
    for (int f=0; f<13; ++f) s_ += xr[1+f]*cw[o*13+f];
    fu = s_ > 0.f ? s_ : 0.f;
  }
  float part = fu*aw[l] + (l==0 ? fu64*aw[64] : 0.f);
  #pragma unroll
  for (int off=32; off; off>>=1) part += __shfl_down(part, off, 64);
  part = __shfl(part, 0, 64);
  float attn = sigf(part + ab[0]);
  int i_ = r / NT, tau = r % NT;          // scrambled reshape (B*N, T, 65)
  float* zr = ztm + ((size_t)tau*ROWS + i_)*ZSTR;
  zr[l] = fu*attn;
  if (l == 0) zr[64] = fu64*attn;         // pad cols 65..79 multiply zero weights
  if (t == NT-1){
    if (l >= 33) ctx[(size_t)(b*NNODE+n)*32 + (l-33)] = fu;
    if (l == 0){ ctx[(size_t)(b*NNODE+n)*32 + 31] = fu64; pred0[b*NNODE+n] = xr[0]; }
  }
}

__global__ __launch_bounds__(256) void k_out(const float* __restrict__ preds, float* __restrict__ out){
  int idx = blockIdx.x*256 + threadIdx.x;
  if (idx >= NT*ROWS) return;
  int n = idx % NNODE;
  int t2 = idx / NNODE;
  int hor = t2 % NT;
  int b = t2 / NT;
  out[idx] = preds[(size_t)hor*ROWS + b*NNODE + n];
}

extern "C" void kernel_launch(void* const* d_in, const int* in_sizes, int n_in,
                              void* d_out, int out_size, void* d_ws, size_t ws_size,
                              hipStream_t stream){
  const float* x     = (const float*)d_in[0];
  const float* Aph   = (const float*)d_in[1];
  const float* fcw   = (const float*)d_in[2];
  const float* fcb   = (const float*)d_in[3];
  const float* alp   = (const float*)d_in[4];
  const float* cw    = (const float*)d_in[5];
  const float* cb    = (const float*)d_in[6];
  const float* tw    = (const float*)d_in[7];
  const float* tb    = (const float*)d_in[8];
  const float* theta = (const float*)d_in[9];
  const float* aw    = (const float*)d_in[10];
  const float* ab    = (const float*)d_in[11];
  const float* ewih  = (const float*)d_in[12];
  const float* ewhh  = (const float*)d_in[13];
  const float* ebih  = (const float*)d_in[14];
  const float* ebhh  = (const float*)d_in[15];
  const float* dwih  = (const float*)d_in[16];
  const float* dwhh  = (const float*)d_in[17];
  const float* dbih  = (const float*)d_in[18];
  const float* dbhh  = (const float*)d_in[19];
  const float* ow    = (const float*)d_in[20];
  const float* ob    = (const float*)d_in[21];
  float* out = (float*)d_out;

  const size_t SZ_H    = (size_t)ROWS*NH;
  const size_t SZ_CTX  = (size_t)ROWS*32;
  const size_t SZ_PRED = (size_t)ROWS;
  const size_t SZ_PREDS= (size_t)NT*ROWS;
  const size_t SZ_G    = (size_t)ROWS*G3;
  const size_t SZ_ABUF = (size_t)NB*NNODE*LSTR;
  const size_t SZ_EMB  = (size_t)ROWS*16;
  const size_t SZ_Z    = (size_t)NT*ROWS*ZSTR;   // 25.4M >= 2*SZ_G

  float* w = (float*)d_ws;
  size_t off = 0;
  auto alloc = [&](size_t nfl){ float* p = w + off; off += nfl; return p; };
  float* h     = alloc(SZ_H);
  float* ctx   = alloc(SZ_CTX);
  float* pred  = alloc(SZ_PRED);
  float* preds = alloc(SZ_PREDS);
  float* Abuf  = alloc(SZ_ABUF);
  float* emb   = alloc(SZ_EMB);
  float* rsum  = alloc(SZ_PRED);
  float* lam   = alloc((size_t)NB);
  float* wt    = alloc((size_t)WT_TOTAL);
  float* Sslot = alloc(SZ_G);      // t_feat -> S -> ctxGX
  float* Zzone = alloc(SZ_Z);      // P1 | P2 ; later z (tau,i,ZSTR)
  float* P1 = Zzone;
  float* P2 = Zzone + SZ_G;
  (void)n_in; (void)in_sizes;

  if (ws_size < off*sizeof(float)){    // tripwire: workspace too small
    k_sentinel<<<(out_size+255)/256, 256, 0, stream>>>(out, out_size);
    return;
  }

  float* WENC  = wt + OFF_WENC;
  float* dwhhT = wt + OFF_DWHHT;
  float* dwihT = wt + OFF_DWIHT;
  float* w0    = wt + OFF_W0;

  k_prep<<<(WT_TOTAL+255)/256, 256, 0, stream>>>(ewih, ewhh, dwih, dwhh, wt);
  float* tfeat = Sslot;
  k_emb<<<(ROWS*16)/256, 256, 0, stream>>>(x, fcw, fcb, emb);
  k_adj<<<ROWS/4, 256, 0, stream>>>(emb, Aph, alp, Abuf, rsum);
  k_lam<<<NB, 256, 0, stream>>>(rsum, lam);
  k_lap<<<(NB*NNODE*LSTR)/256, 256, 0, stream>>>(Abuf, lam);
  k_tcn<<<(BTN*32)/256, 256, 0, stream>>>(x, tw, tb, tfeat);
  k_thetaBC<<<BTN/8, 256, 0, stream>>>(tfeat, theta, P2, P1);
  // P2 <- 2*(L @ P1) + P2
  gemm128<<<dim3(3, 2, NB), 256, 0, stream>>>(Abuf, LSTR, (long long)NNODE*LSTR,
      P1, (long long)NNODE*G3, nullptr,
      P2, (long long)NNODE*G3, 2.f, 1.f, 0,
      P2, (long long)NNODE*G3, NNODE, 13);
  k_thetaA<<<BTN/8, 256, 0, stream>>>(tfeat, theta, P1);
  // Sslot <- relu((L @ P2) + P1)
  gemm128<<<dim3(3, 2, NB), 256, 0, stream>>>(Abuf, LSTR, (long long)NNODE*LSTR,
      P2, (long long)NNODE*G3, nullptr,
      P1, (long long)NNODE*G3, 1.f, 1.f, 1,
      Sslot, (long long)NNODE*G3, NNODE, 13);
  k_zbuild<<<BTN/4, 256, 0, stream>>>(x, Sslot, cw, cb, aw, ab, Zzone, ctx, pred);
  hipMemsetAsync(h, 0, SZ_H*sizeof(float), stream);

  for (int t=0; t<NT; ++t){
    k_enc_fused2<<<ROWS/64, 512, 0, stream>>>(h, Zzone + (size_t)t*ROWS*ZSTR,
        WENC, ebih, ebhh);
  }
  float* ctxGX = Sslot;  // S dead after zbuild
  gemm128<<<dim3(3, ROWS/128, 1), 256, 0, stream>>>(
      ctx, 32, 0, dwihT, 0, dbih,
      nullptr, 0, 1.f, 0.f, 0, ctxGX, 0, ROWS, 2);
  for (int s=0; s<NT; ++s){
    k_dec_fused2<<<ROWS/64, 512, 0, stream>>>(h, dwhhT, dbhh, ctxGX, w0, ow, ob,
        pred, preds + (size_t)s*ROWS);
  }
  k_out<<<(NT*ROWS)/256, 256, 0, stream>>>(preds, out);
}

// Round 7
// 1047.539 us; speedup vs baseline: 2.4409x; 2.1967x over previous
//
#include <hip/hip_runtime.h>
#include <math.h>

#define NB 128      // B
#define NT 12       // T
#define NNODE 207   // N
#define NF 14       // F
#define NH 128      // H
#define ROWS (NB*NNODE)      // 26496
#define BTN (NB*NT*NNODE)    // 317952
#define G3 (3*NH)            // 384
#define LSTR 208             // padded Laplacian row stride
#define ZSTR 80              // padded z row stride

typedef __attribute__((ext_vector_type(8))) short short8;   // 8 bf16 = 4 VGPR
typedef __attribute__((ext_vector_type(4))) float accf4;    // MFMA C/D

#define MFMA16 __builtin_amdgcn_mfma_f32_16x16x32_bf16

__device__ __forceinline__ float sigf(float x){ return 1.0f/(1.0f+__expf(-x)); }
__device__ __forceinline__ unsigned short f2b(float f){
  unsigned int u = __float_as_uint(f);
  return (unsigned short)((u + 0x7FFFu + ((u>>16)&1u)) >> 16);
}
__device__ __forceinline__ float b2f(unsigned short h){
  return __uint_as_float(((unsigned int)h) << 16);
}
__device__ __forceinline__ void mm4(short8 ah, short8 al, short8 bh, short8 bl, accf4& acc){
  acc = MFMA16(ah, bh, acc, 0,0,0);
  acc = MFMA16(al, bh, acc, 0,0,0);
  acc = MFMA16(ah, bl, acc, 0,0,0);
  acc = MFMA16(al, bl, acc, 0,0,0);
}

__global__ __launch_bounds__(256) void k_sentinel(float* __restrict__ out, int n){
  int i = blockIdx.x*256 + threadIdx.x;
  if (i < n) out[i] = 12345.0f;
}

// ---- weight prep ----
// WFH/WFL: encoder frag-layout bf16 hi/lo, 7 ksteps x 24 coltiles x 64 lanes x 8
//   K layout: 0..64 = ewih^T, 65..95 = 0, 96..223 = ewhh^T
// DFH/DFL: decoder (dwhh^T), 4 ksteps
// wf: dwihT (32x384 fp32) + w0 (384)
#define NW_ENC (7*24*64*8)   // 86016
#define NW_DEC (4*24*64*8)   // 49152
#define SH_TOTAL (2*NW_ENC + 2*NW_DEC)   // 270336 shorts = 135168 floats
#define FWT_TOTAL (32*384 + 384)         // 12672 floats
#define PREP_TOTAL (NW_ENC + NW_DEC + 32*384 + 384)   // 147840
__global__ __launch_bounds__(256) void k_prep(const float* __restrict__ ewih,
    const float* __restrict__ ewhh, const float* __restrict__ dwih,
    const float* __restrict__ dwhh, short* __restrict__ ws, float* __restrict__ wf){
  int i = blockIdx.x*256 + threadIdx.x;
  if (i < NW_ENC){
    int e = i & 7, lane = (i>>3) & 63, ct = (i>>9) % 24, ks = i / 12288;
    int k = ks*32 + (lane>>4)*8 + e;
    int col = ct*16 + (lane&15);
    float wv = (k < 65) ? ewih[col*65 + k] : ((k < 96) ? 0.f : ewhh[col*128 + (k-96)]);
    unsigned short hi = f2b(wv);
    ws[i] = (short)hi;
    ws[NW_ENC + i] = (short)f2b(wv - b2f(hi));
  } else if (i < NW_ENC + NW_DEC){
    int j = i - NW_ENC;
    int e = j & 7, lane = (j>>3) & 63, ct = (j>>9) % 24, ks = j / 12288;
    int k = ks*32 + (lane>>4)*8 + e;
    int col = ct*16 + (lane&15);
    float wv = dwhh[col*128 + k];
    unsigned short hi = f2b(wv);
    ws[2*NW_ENC + j] = (short)hi;
    ws[2*NW_ENC + NW_DEC + j] = (short)f2b(wv - b2f(hi));
  } else if (i < NW_ENC + NW_DEC + 32*384){
    int j = i - (NW_ENC + NW_DEC); int k = j/384, n = j%384;
    wf[j] = dwih[n*33 + 1 + k];
  } else if (i < PREP_TOTAL){
    int n = i - (NW_ENC + NW_DEC + 32*384);
    wf[32*384 + n] = dwih[n*33];
  }
}

// emb = tanh(state * fc_w + fc_b)
__global__ __launch_bounds__(256) void k_emb(const float* __restrict__ x,
    const float* __restrict__ w, const float* __restrict__ b, float* __restrict__ emb){
  int idx = blockIdx.x*256 + threadIdx.x;
  if (idx >= ROWS*16) return;
  int j = idx & 15, row = idx >> 4;
  int bb = row / NNODE, n = row % NNODE;
  float s = x[((bb*NT + (NT-1))*NNODE + n)*NF];
  emb[idx] = tanhf(s*w[j] + b[j]);
}

// wave-per-row adjacency: top-10, sparse softmax, blend, rowsum
__global__ __launch_bounds__(256) void k_adj(const float* __restrict__ emb,
    const float* __restrict__ Aph, const float* __restrict__ alp,
    float* __restrict__ Abuf, float* __restrict__ rsum){
  int wid = threadIdx.x >> 6, lane = threadIdx.x & 63;
  int row = blockIdx.x*4 + wid;
  int bb = row / NNODE, n = row % NNODE;
  const float4* er = (const float4*)(emb + (size_t)row*16);
  float4 e0 = er[0], e1 = er[1], e2 = er[2], e3 = er[3];
  float d[4];
  #pragma unroll
  for (int q=0;q<4;++q){
    int m = lane + q*64;
    float dd = -1.f;
    if (m < NNODE){
      const float4* em = (const float4*)(emb + (size_t)(bb*NNODE+m)*16);
      float4 m0 = em[0], m1 = em[1], m2 = em[2], m3 = em[3];
      dd = e0.x*m0.x + e0.y*m0.y + e0.z*m0.z + e0.w*m0.w
         + e1.x*m1.x + e1.y*m1.y + e1.z*m1.z + e1.w*m1.w
         + e2.x*m2.x + e2.y*m2.y + e2.z*m2.z + e2.w*m2.w
         + e3.x*m3.x + e3.y*m3.y + e3.z*m3.z + e3.w*m3.w;
      dd = dd > 0.f ? dd : 0.f;
    }
    d[q] = dd;
  }
  int km = 0;
  float vmax = 0.f;
  for (int it=0; it<10; ++it){
    float v = -1.f; int mi = 1<<20;
    #pragma unroll
    for (int q=0;q<4;++q){
      if (d[q] >= 0.f && !((km>>q)&1) && d[q] > v){ v = d[q]; mi = lane + q*64; }
    }
    #pragma unroll
    for (int off=1; off<64; off<<=1){
      float v2 = __shfl_xor(v, off, 64);
      int  i2 = __shfl_xor(mi, off, 64);
      if (v2 > v || (v2 == v && i2 < mi)){ v = v2; mi = i2; }
    }
    if (it == 0) vmax = v;
    if ((mi & 63) == lane) km |= 1 << (mi >> 6);
  }
  float a = sigf(alp[0]);
  float eneg = __expf(-vmax);
  float p[4]; float ps = 0.f;
  #pragma unroll
  for (int q=0;q<4;++q){
    p[q] = 0.f;
    if (d[q] >= 0.f) p[q] = ((km>>q)&1) ? __expf(d[q]-vmax) : eneg;
    ps += p[q];
  }
  #pragma unroll
  for (int off=1; off<64; off<<=1) ps += __shfl_xor(ps, off, 64);
  float inv = (1.f - a)/ps;
  float rs = 0.f;
  #pragma unroll
  for (int q=0;q<4;++q){
    int m = lane + q*64;
    if (m < NNODE){
      float Av = a*Aph[n*NNODE + m] + p[q]*inv;
      Abuf[(size_t)row*LSTR + m] = Av;
      rs += Av;
    }
  }
  if (lane == 0) Abuf[(size_t)row*LSTR + 207] = 0.f;
  #pragma unroll
  for (int off=1; off<64; off<<=1) rs += __shfl_xor(rs, off, 64);
  if (lane == 0) rsum[row] = rs;
}

__global__ __launch_bounds__(256) void k_lam(const float* __restrict__ rsum, float* __restrict__ lam){
  __shared__ float rv[256];
  int b = blockIdx.x, tid = threadIdx.x;
  rv[tid] = (tid < NNODE) ? rsum[b*NNODE+tid] : -1e30f;
  __syncthreads();
  for (int s=128;s>0;s>>=1){ if (tid<s) rv[tid]=fmaxf(rv[tid],rv[tid+s]); __syncthreads(); }
  if (tid==0) lam[b] = fmaxf(rv[0], 1.0f);
}

__global__ __launch_bounds__(256) void k_lap(float* __restrict__ Abuf, const float* __restrict__ lam){
  int idx = blockIdx.x*256 + threadIdx.x;
  if (idx >= NB*NNODE*LSTR) return;
  int b = idx / (NNODE*LSTR);
  int rem = idx % (NNODE*LSTR);
  int n = rem / LSTR, m = rem % LSTR;
  Abuf[idx] = 2.f*Abuf[idx]/lam[b] - (n==m ? 1.f : 0.f);
}

// causal conv(3) + GLU
__global__ __launch_bounds__(256) void k_tcn(const float* __restrict__ x,
    const float* __restrict__ w, const float* __restrict__ bcn, float* __restrict__ tfeat){
  int idx = blockIdx.x*256 + threadIdx.x;
  if (idx >= BTN*32) return;
  int o = idx & 31; int r = idx >> 5;
  int n = r % NNODE, bt = r / NNODE, t = bt % NT, b = bt / NT;
  float t0 = (t>=2)? x[((size_t)(b*NT+t-2)*NNODE+n)*NF] : 0.f;
  float t1 = (t>=1)? x[((size_t)(b*NT+t-1)*NNODE+n)*NF] : 0.f;
  float t2 = x[((size_t)(b*NT+t)*NNODE+n)*NF];
  float P = bcn[o]    + w[o*3]*t0       + w[o*3+1]*t1       + w[o*3+2]*t2;
  float Q = bcn[o+32] + w[(o+32)*3]*t0  + w[(o+32)*3+1]*t1  + w[(o+32)*3+2]*t2;
  tfeat[(size_t)r*32 + o] = P * sigf(Q);
}

__global__ __launch_bounds__(256) void k_thetaBC(const float* __restrict__ tfeat,
    const float* __restrict__ theta, float* __restrict__ P2, float* __restrict__ P1){
  __shared__ float thB[32][33], thC[32][33];
  __shared__ float tf[8][32];
  int tid = threadIdx.x;
  for (int i=tid; i<1024; i+=256){
    int f = i >> 5, o = i & 31;
    thB[o][f] = theta[1024+f*32+o]; thC[o][f] = theta[2048+f*32+o];
  }
  int rl = tid >> 5, o = tid & 31;
  int r = blockIdx.x*8 + rl;
  tf[rl][o] = tfeat[(size_t)r*32 + o];
  __syncthreads();
  float aB=0.f, aC=0.f;
  #pragma unroll
  for (int f=0; f<32; ++f){
    float t = tf[rl][f];
    aB += t*thB[o][f]; aC += t*thC[o][f];
  }
  int n = r % NNODE, bt = r / NNODE, t = bt % NT, b = bt / NT;
  size_t outi = (size_t)(b*NNODE+n)*G3 + t*32 + o;
  P2[outi]=aB; P1[outi]=aC;
}

__global__ __launch_bounds__(256) void k_thetaA(const float* __restrict__ tfeat,
    const float* __restrict__ theta, float* __restrict__ P1){
  __shared__ float thA[32][33];
  __shared__ float tf[8][32];
  int tid = threadIdx.x;
  for (int i=tid; i<1024; i+=256){
    int f = i >> 5, o = i & 31;
    thA[o][f] = theta[f*32+o] - theta[2048+f*32+o];
  }
  int rl = tid >> 5, o = tid & 31;
  int r = blockIdx.x*8 + rl;
  tf[rl][o] = tfeat[(size_t)r*32 + o];
  __syncthreads();
  float aA=0.f;
  #pragma unroll
  for (int f=0; f<32; ++f) aA += tf[rl][f]*thA[o][f];
  int n = r % NNODE, bt = r / NNODE, t = bt % NT, b = bt / NT;
  P1[(size_t)(b*NNODE+n)*G3 + t*32 + o] = aA;
}

// ---- fp32 128x128 GEMM (Chebyshev + ctxGX) ----
__global__ __launch_bounds__(256) void gemm128(
    const float* __restrict__ Ab, int lda, long long sA,
    const float* __restrict__ Bb, long long sB,
    const float* __restrict__ bias,
    const float* __restrict__ Yb, long long sY, float alphaV, float betaV, int do_relu,
    float* __restrict__ Cb, long long sC, int M, int kchunks){
  __shared__ float As[16][132];
  __shared__ float Bs[16][132];
  int bz = blockIdx.z;
  const float* A = Ab + (size_t)bz*sA;
  const float* B = Bb + (size_t)bz*sB;
  float* C = Cb + (size_t)bz*sC;
  int n0 = blockIdx.x*128, m0 = blockIdx.y*128;
  int tid = threadIdx.x, tx = tid & 15, ty = tid >> 4;
  float acc[8][8] = {};
  int ar = tid & 127, ak = (tid >> 7)*8;
  int bk = tid >> 4, bn = (tid & 15)*8;
  for (int kc=0; kc<kchunks; ++kc){
    int k0 = kc*16;
    int m = m0 + ar;
    if (m < M){
      const float* ap = A + (size_t)m*lda + k0 + ak;
      float4 v0 = *(const float4*)ap, v1 = *(const float4*)(ap+4);
      As[ak+0][ar]=v0.x; As[ak+1][ar]=v0.y; As[ak+2][ar]=v0.z; As[ak+3][ar]=v0.w;
      As[ak+4][ar]=v1.x; As[ak+5][ar]=v1.y; As[ak+6][ar]=v1.z; As[ak+7][ar]=v1.w;
    } else {
      #pragma unroll
      for (int j=0;j<8;++j) As[ak+j][ar]=0.f;
    }
    const float* bp = B + (size_t)(k0+bk)*384 + n0 + bn;
    float4 w0_ = *(const float4*)bp, w1_ = *(const float4*)(bp+4);
    *(float4*)&Bs[bk][bn] = w0_; *(float4*)&Bs[bk][bn+4] = w1_;
    __syncthreads();
    #pragma unroll
    for (int kk=0;kk<16;++kk){
      float4 a0 = *(const float4*)&As[kk][ty*8];
      float4 a1 = *(const float4*)&As[kk][ty*8+4];
      float4 b0 = *(const float4*)&Bs[kk][tx*4];
      float4 b1 = *(const float4*)&Bs[kk][64+tx*4];
      float av[8] = {a0.x,a0.y,a0.z,a0.w,a1.x,a1.y,a1.z,a1.w};
      float bv[8] = {b0.x,b0.y,b0.z,b0.w,b1.x,b1.y,b1.z,b1.w};
      #pragma unroll
      for (int i=0;i<8;++i)
        #pragma unroll
        for (int j=0;j<8;++j) acc[i][j] += av[i]*bv[j];
    }
    __syncthreads();
  }
  if (bias){
    float bl[4], bh_[4];
    #pragma unroll
    for (int j=0;j<4;++j){ bl[j]=bias[n0+tx*4+j]; bh_[j]=bias[n0+64+tx*4+j]; }
    #pragma unroll
    for (int i=0;i<8;++i){
      int m2 = m0 + ty*8 + i; if (m2 >= M) continue;
      float4 s0, s1;
      s0.x=acc[i][0]+bl[0]; s0.y=acc[i][1]+bl[1]; s0.z=acc[i][2]+bl[2]; s0.w=acc[i][3]+bl[3];
      s1.x=acc[i][4]+bh_[0]; s1.y=acc[i][5]+bh_[1]; s1.z=acc[i][6]+bh_[2]; s1.w=acc[i][7]+bh_[3];
      *(float4*)&C[(size_t)m2*384 + n0 + tx*4] = s0;
      *(float4*)&C[(size_t)m2*384 + n0 + 64 + tx*4] = s1;
    }
  } else {
    const float* Y = Yb + (size_t)bz*sY;
    #pragma unroll
    for (int i=0;i<8;++i){
      int m2 = m0 + ty*8 + i; if (m2 >= M) continue;
      const float* yr = Y + (size_t)m2*384;
      float* cr = C + (size_t)m2*384;
      float4 y0 = *(const float4*)(yr + n0 + tx*4);
      float4 y1 = *(const float4*)(yr + n0 + 64 + tx*4);
      float4 s0, s1;
      s0.x = alphaV*acc[i][0] + betaV*y0.x; s0.y = alphaV*acc[i][1] + betaV*y0.y;
      s0.z = alphaV*acc[i][2] + betaV*y0.z; s0.w = alphaV*acc[i][3] + betaV*y0.w;
      s1.x = alphaV*acc[i][4] + betaV*y1.x; s1.y = alphaV*acc[i][5] + betaV*y1.y;
      s1.z = alphaV*acc[i][6] + betaV*y1.z; s1.w = alphaV*acc[i][7] + betaV*y1.w;
      if (do_relu){
        s0.x=fmaxf(s0.x,0.f); s0.y=fmaxf(s0.y,0.f); s0.z=fmaxf(s0.z,0.f); s0.w=fmaxf(s0.w,0.f);
        s1.x=fmaxf(s1.x,0.f); s1.y=fmaxf(s1.y,0.f); s1.z=fmaxf(s1.z,0.f); s1.w=fmaxf(s1.w,0.f);
      }
      *(float4*)(cr + n0 + tx*4) = s0;
      *(float4*)(cr + n0 + 64 + tx*4) = s1;
    }
  }
}

// ===================== MFMA fused encoder step =====================
// 64 rows x 384 gate-cols per block, 512 threads (8 waves).
// Wave w owns h-col slice j in [16w,16w+16); C-tiles: r(ct=w), z(ct=8+w), n(ct=16+w)
// K: ksteps 0-2 = z (80 + zero-pad to 96), ksteps 3-6 = h (128).
#define A_STRIDE 40   // shorts per LDS row (80B: 16B-aligned frags, 2-way banks)
__global__ __launch_bounds__(512) void k_enc_mfma(float* __restrict__ h,
    const float* __restrict__ zt, const short* __restrict__ WFH,
    const short* __restrict__ WFL, const float* __restrict__ bih,
    const float* __restrict__ bhh){
  __shared__ short Ahi[64*A_STRIDE];
  __shared__ short Alo[64*A_STRIDE];
  int m0 = blockIdx.x*64;
  int tid = threadIdx.x;
  int w = tid >> 6, lane = tid & 63;
  int g = lane >> 4, c = lane & 15;
  accf4 accR[4] = {}, accZ[4] = {}, accNZ[4] = {}, accNH[4] = {};
  int srow = tid >> 3, skq = (tid & 7)*4;
  int fbase = c*A_STRIDE + g*8;

#define STAGE_SPLIT(V) { \
    ushort4 hv4, lv4; \
    hv4.x = f2b(V.x); lv4.x = f2b(V.x - b2f(hv4.x)); \
    hv4.y = f2b(V.y); lv4.y = f2b(V.y - b2f(hv4.y)); \
    hv4.z = f2b(V.z); lv4.z = f2b(V.z - b2f(hv4.z)); \
    hv4.w = f2b(V.w); lv4.w = f2b(V.w - b2f(hv4.w)); \
    *(ushort4*)&Ahi[srow*A_STRIDE + skq] = hv4; \
    *(ushort4*)&Alo[srow*A_STRIDE + skq] = lv4; }

#define ENC_KS(KS, ACCN) { \
    const int ko = (KS)*24; \
    short8 bRh = *(const short8*)(WFH + ((ko + w)*64 + lane)*8); \
    short8 bZh = *(const short8*)(WFH + ((ko + 8 + w)*64 + lane)*8); \
    short8 bNh = *(const short8*)(WFH + ((ko + 16 + w)*64 + lane)*8); \
    short8 bRl = *(const short8*)(WFL + ((ko + w)*64 + lane)*8); \
    short8 bZl = *(const short8*)(WFL + ((ko + 8 + w)*64 + lane)*8); \
    short8 bNl = *(const short8*)(WFL + ((ko + 16 + w)*64 + lane)*8); \
    _Pragma("unroll") \
    for (int rt=0; rt<4; ++rt){ \
      short8 ah = *(const short8*)&Ahi[rt*16*A_STRIDE + fbase]; \
      short8 al = *(const short8*)&Alo[rt*16*A_STRIDE + fbase]; \
      mm4(ah, al, bRh, bRl, accR[rt]); \
      mm4(ah, al, bZh, bZl, accZ[rt]); \
      mm4(ah, al, bNh, bNl, ACCN[rt]); \
    } }

  #pragma unroll
  for (int ks=0; ks<3; ++ks){
    __syncthreads();
    int k = ks*32 + skq;
    float4 v = make_float4(0.f,0.f,0.f,0.f);
    if (k < 80) v = *(const float4*)&zt[(size_t)(m0+srow)*ZSTR + k];
    STAGE_SPLIT(v);
    __syncthreads();
    ENC_KS(ks, accNZ);
  }
  #pragma unroll
  for (int ks=3; ks<7; ++ks){
    __syncthreads();
    int k = (ks-3)*32 + skq;
    float4 v = *(const float4*)&h[(size_t)(m0+srow)*NH + k];
    STAGE_SPLIT(v);
    __syncthreads();
    ENC_KS(ks, accNH);
  }
  int j = (w<<4) + c;
  float birv = bih[j], bizv = bih[128+j], binv = bih[256+j];
  float bhrv = bhh[j], bhzv = bhh[128+j], bhnv = bhh[256+j];
  #pragma unroll
  for (int rt=0; rt<4; ++rt){
    #pragma unroll
    for (int i=0;i<4;++i){
      int row = m0 + rt*16 + g*4 + i;
      float r_ = sigf(accR[rt][i] + birv + bhrv);
      float z_ = sigf(accZ[rt][i] + bizv + bhzv);
      float n_ = tanhf(accNZ[rt][i] + binv + r_*(accNH[rt][i] + bhnv));
      float ho = h[(size_t)row*NH + j];
      h[(size_t)row*NH + j] = (1.f - z_)*n_ + z_*ho;
    }
  }
}

// ===================== MFMA fused decoder step =====================
__global__ __launch_bounds__(512) void k_dec_mfma(float* __restrict__ h,
    const short* __restrict__ DFH, const short* __restrict__ DFL,
    const float* __restrict__ dbhh, const float* __restrict__ ctxGX,
    const float* __restrict__ w0, const float* __restrict__ ow,
    const float* __restrict__ ob,
    float* __restrict__ pred, float* __restrict__ preds_out){
  __shared__ short Ahi[64*A_STRIDE];
  __shared__ short Alo[64*A_STRIDE];
  __shared__ float psl[8][64];
  int m0 = blockIdx.x*64;
  int tid = threadIdx.x;
  int w = tid >> 6, lane = tid & 63;
  int g = lane >> 4, c = lane & 15;
  accf4 accR[4] = {}, accZ[4] = {}, accN[4] = {};
  int srow = tid >> 3, skq = (tid & 7)*4;
  int fbase = c*A_STRIDE + g*8;
  #pragma unroll
  for (int ks=0; ks<4; ++ks){
    __syncthreads();
    float4 v = *(const float4*)&h[(size_t)(m0+srow)*NH + ks*32 + skq];
    STAGE_SPLIT(v);
    __syncthreads();
    const int ko = ks*24;
    short8 bRh = *(const short8*)(DFH + ((ko + w)*64 + lane)*8);
    short8 bZh = *(const short8*)(DFH + ((ko + 8 + w)*64 + lane)*8);
    short8 bNh = *(const short8*)(DFH + ((ko + 16 + w)*64 + lane)*8);
    short8 bRl = *(const short8*)(DFL + ((ko + w)*64 + lane)*8);
    short8 bZl = *(const short8*)(DFL + ((ko + 8 + w)*64 + lane)*8);
    short8 bNl = *(const short8*)(DFL + ((ko + 16 + w)*64 + lane)*8);
    #pragma unroll
    for (int rt=0; rt<4; ++rt){
      short8 ah = *(const short8*)&Ahi[rt*16*A_STRIDE + fbase];
      short8 al = *(const short8*)&Alo[rt*16*A_STRIDE + fbase];
      mm4(ah, al, bRh, bRl, accR[rt]);
      mm4(ah, al, bZh, bZl, accZ[rt]);
      mm4(ah, al, bNh, bNl, accN[rt]);
    }
  }
  int j = (w<<4) + c;
  float w0r = w0[j], w0z = w0[128+j], w0n = w0[256+j];
  float bhr = dbhh[j], bhz = dbhh[128+j], bhn = dbhh[256+j];
  float owj = ow[j];
  #pragma unroll
  for (int rt=0; rt<4; ++rt){
    #pragma unroll
    for (int i=0;i<4;++i){
      int row = m0 + rt*16 + g*4 + i;
      float p = pred[row];
      const float* gx = ctxGX + (size_t)row*384;
      float r_ = sigf(gx[j]     + p*w0r + accR[rt][i] + bhr);
      float z_ = sigf(gx[128+j] + p*w0z + accZ[rt][i] + bhz);
      float n_ = tanhf(gx[256+j] + p*w0n + r_*(accN[rt][i] + bhn));
      float ho = h[(size_t)row*NH + j];
      float hn = (1.f - z_)*n_ + z_*ho;
      h[(size_t)row*NH + j] = hn;
      float psv = hn*owj;
      psv += __shfl_xor(psv, 1, 64);
      psv += __shfl_xor(psv, 2, 64);
      psv += __shfl_xor(psv, 4, 64);
      psv += __shfl_xor(psv, 8, 64);
      if (c == 0) psl[w][rt*16 + g*4 + i] = psv;
    }
  }
  __syncthreads();
  if (tid < 64){
    float s = ob[0];
    #pragma unroll
    for (int w2=0; w2<8; ++w2) s += psl[w2][tid];
    pred[m0+tid] = s;
    preds_out[m0+tid] = s;
  }
}

// fusion, attn gate, write z (tau, i, ZSTR) + zero pad cols 65..79 + ctx + pred0
__global__ __launch_bounds__(256) void k_zbuild(const float* __restrict__ x,
    const float* __restrict__ S, const float* __restrict__ cw, const float* __restrict__ cb,
    const float* __restrict__ aw, const float* __restrict__ ab,
    float* __restrict__ ztm, float* __restrict__ ctx, float* __restrict__ pred0){
  int tid = threadIdx.x;
  int rl = tid >> 6, l = tid & 63;
  int r = blockIdx.x*4 + rl;
  int n = r % NNODE, bt = r / NNODE, t = bt % NT, b = bt / NT;
  const float* xr = x + (size_t)r*NF;
  float fu, fu64 = 0.f;
  if (l == 0){
    fu = xr[0];
    float s_ = cb[31];
    #pragma unroll
    for (int f=0; f<13; ++f) s_ += xr[1+f]*cw[31*13+f];
    fu64 = s_ > 0.f ? s_ : 0.f;
  } else if (l < 33){
    fu = S[(size_t)(b*NNODE+n)*G3 + t*32 + (l-1)];
  } else {
    int o = l - 33;
    float s_ = cb[o];
    #pragma unroll
    for (int f=0; f<13; ++f) s_ += xr[1+f]*cw[o*13+f];
    fu = s_ > 0.f ? s_ : 0.f;
  }
  float part = fu*aw[l] + (l==0 ? fu64*aw[64] : 0.f);
  #pragma unroll
  for (int off=32; off; off>>=1) part += __shfl_down(part, off, 64);
  part = __shfl(part, 0, 64);
  float attn = sigf(part + ab[0]);
  int i_ = r / NT, tau = r % NT;          // scrambled reshape (B*N, T, 65)
  float* zr = ztm + ((size_t)tau*ROWS + i_)*ZSTR;
  zr[l] = fu*attn;
  if (l == 0) zr[64] = fu64*attn;
  if (l >= 1 && l <= 15) zr[64 + l] = 0.f;   // zero pad cols 65..79 (MFMA safety)
  if (t == NT-1){
    if (l >= 33) ctx[(size_t)(b*NNODE+n)*32 + (l-33)] = fu;
    if (l == 0){ ctx[(size_t)(b*NNODE+n)*32 + 31] = fu64; pred0[b*NNODE+n] = xr[0]; }
  }
}

__global__ __launch_bounds__(256) void k_out(const float* __restrict__ preds, float* __restrict__ out){
  int idx = blockIdx.x*256 + threadIdx.x;
  if (idx >= NT*ROWS) return;
  int n = idx % NNODE;
  int t2 = idx / NNODE;
  int hor = t2 % NT;
  int b = t2 / NT;
  out[idx] = preds[(size_t)hor*ROWS + b*NNODE + n];
}

extern "C" void kernel_launch(void* const* d_in, const int* in_sizes, int n_in,
                              void* d_out, int out_size, void* d_ws, size_t ws_size,
                              hipStream_t stream){
  const float* x     = (const float*)d_in[0];
  const float* Aph   = (const float*)d_in[1];
  const float* fcw   = (const float*)d_in[2];
  const float* fcb   = (const float*)d_in[3];
  const float* alp   = (const float*)d_in[4];
  const float* cw    = (const float*)d_in[5];
  const float* cb    = (const float*)d_in[6];
  const float* tw    = (const float*)d_in[7];
  const float* tb    = (const float*)d_in[8];
  const float* theta = (const float*)d_in[9];
  const float* aw    = (const float*)d_in[10];
  const float* ab    = (const float*)d_in[11];
  const float* ewih  = (const float*)d_in[12];
  const float* ewhh  = (const float*)d_in[13];
  const float* ebih  = (const float*)d_in[14];
  const float* ebhh  = (const float*)d_in[15];
  const float* dwih  = (const float*)d_in[16];
  const float* dwhh  = (const float*)d_in[17];
  const float* dbih  = (const float*)d_in[18];
  const float* dbhh  = (const float*)d_in[19];
  const float* ow    = (const float*)d_in[20];
  const float* ob    = (const float*)d_in[21];
  float* out = (float*)d_out;

  const size_t SZ_H    = (size_t)ROWS*NH;
  const size_t SZ_CTX  = (size_t)ROWS*32;
  const size_t SZ_PRED = (size_t)ROWS;
  const size_t SZ_PREDS= (size_t)NT*ROWS;
  const size_t SZ_G    = (size_t)ROWS*G3;
  const size_t SZ_ABUF = (size_t)NB*NNODE*LSTR;
  const size_t SZ_EMB  = (size_t)ROWS*16;
  const size_t SZ_Z    = (size_t)NT*ROWS*ZSTR;   // >= 2*SZ_G

  float* w = (float*)d_ws;
  size_t off = 0;
  auto alloc = [&](size_t nfl){ float* p = w + off; off += nfl; return p; };
  float* h     = alloc(SZ_H);
  float* ctx   = alloc(SZ_CTX);
  float* pred  = alloc(SZ_PRED);
  float* preds = alloc(SZ_PREDS);
  float* Abuf  = alloc(SZ_ABUF);
  float* emb   = alloc(SZ_EMB);
  float* rsum  = alloc(SZ_PRED);
  float* lam   = alloc((size_t)NB);
  short* wS    = (short*)alloc(SH_TOTAL/2);
  float* wF    = alloc((size_t)FWT_TOTAL);
  float* Sslot = alloc(SZ_G);      // t_feat -> S -> ctxGX
  float* Zzone = alloc(SZ_Z);      // P1 | P2 ; later z
  float* P1 = Zzone;
  float* P2 = Zzone + SZ_G;
  (void)n_in; (void)in_sizes;

  if (ws_size < off*sizeof(float)){    // tripwire: workspace too small
    k_sentinel<<<(out_size+255)/256, 256, 0, stream>>>(out, out_size);
    return;
  }

  const short* WFH = wS;
  const short* WFL = wS + NW_ENC;
  const short* DFH = wS + 2*NW_ENC;
  const short* DFL = wS + 2*NW_ENC + NW_DEC;
  float* dwihT = wF;
  float* w0    = wF + 32*384;

  k_prep<<<(PREP_TOTAL+255)/256, 256, 0, stream>>>(ewih, ewhh, dwih, dwhh, wS, wF);
  float* tfeat = Sslot;
  k_emb<<<(ROWS*16)/256, 256, 0, stream>>>(x, fcw, fcb, emb);
  k_adj<<<ROWS/4, 256, 0, stream>>>(emb, Aph, alp, Abuf, rsum);
  k_lam<<<NB, 256, 0, stream>>>(rsum, lam);
  k_lap<<<(NB*NNODE*LSTR)/256, 256, 0, stream>>>(Abuf, lam);
  k_tcn<<<(BTN*32)/256, 256, 0, stream>>>(x, tw, tb, tfeat);
  k_thetaBC<<<BTN/8, 256, 0, stream>>>(tfeat, theta, P2, P1);
  gemm128<<<dim3(3, 2, NB), 256, 0, stream>>>(Abuf, LSTR, (long long)NNODE*LSTR,
      P1, (long long)NNODE*G3, nullptr,
      P2, (long long)NNODE*G3, 2.f, 1.f, 0,
      P2, (long long)NNODE*G3, NNODE, 13);
  k_thetaA<<<BTN/8, 256, 0, stream>>>(tfeat, theta, P1);
  gemm128<<<dim3(3, 2, NB), 256, 0, stream>>>(Abuf, LSTR, (long long)NNODE*LSTR,
      P2, (long long)NNODE*G3, nullptr,
      P1, (long long)NNODE*G3, 1.f, 1.f, 1,
      Sslot, (long long)NNODE*G3, NNODE, 13);
  k_zbuild<<<BTN/4, 256, 0, stream>>>(x, Sslot, cw, cb, aw, ab, Zzone, ctx, pred);
  hipMemsetAsync(h, 0, SZ_H*sizeof(float), stream);

  for (int t=0; t<NT; ++t){
    k_enc_mfma<<<ROWS/64, 512, 0, stream>>>(h, Zzone + (size_t)t*ROWS*ZSTR,
        WFH, WFL, ebih, ebhh);
  }
  float* ctxGX = Sslot;  // S dead after zbuild
  gemm128<<<dim3(3, ROWS/128, 1), 256, 0, stream>>>(
      ctx, 32, 0, dwihT, 0, dbih,
      nullptr, 0, 1.f, 0.f, 0, ctxGX, 0, ROWS, 2);
  for (int s=0; s<NT; ++s){
    k_dec_mfma<<<ROWS/64, 512, 0, stream>>>(h, DFH, DFL, dbhh, ctxGX, w0, ow, ob,
        pred, preds + (size_t)s*ROWS);
  }
  k_out<<<(NT*ROWS)/256, 256, 0, stream>>>(preds, out);
}

// Round 8
// 905.193 us; speedup vs baseline: 2.8248x; 1.1573x over previous
//
#include <hip/hip_runtime.h>
#include <math.h>

#define NB 128      // B
#define NT 12       // T
#define NNODE 207   // N
#define NF 14       // F
#define NH 128      // H
#define ROWS (NB*NNODE)      // 26496
#define BTN (NB*NT*NNODE)    // 317952
#define G3 (3*NH)            // 384
#define LSTR 208             // padded Laplacian row stride
#define ZSTR 80              // padded z row stride

typedef __attribute__((ext_vector_type(8))) short short8;   // 8 bf16 = 4 VGPR
typedef __attribute__((ext_vector_type(4))) float accf4;    // MFMA C/D

#define MFMA16 __builtin_amdgcn_mfma_f32_16x16x32_bf16

__device__ __forceinline__ float sigf(float x){ return 1.0f/(1.0f+__expf(-x)); }
__device__ __forceinline__ unsigned short f2b(float f){
  unsigned int u = __float_as_uint(f);
  return (unsigned short)((u + 0x7FFFu + ((u>>16)&1u)) >> 16);
}
__device__ __forceinline__ float b2f(unsigned short h){
  return __uint_as_float(((unsigned int)h) << 16);
}
__device__ __forceinline__ void mm4(short8 ah, short8 al, short8 bh, short8 bl, accf4& acc){
  acc = MFMA16(ah, bh, acc, 0,0,0);
  acc = MFMA16(al, bh, acc, 0,0,0);
  acc = MFMA16(ah, bl, acc, 0,0,0);
  acc = MFMA16(al, bl, acc, 0,0,0);
}

__global__ __launch_bounds__(256) void k_sentinel(float* __restrict__ out, int n){
  int i = blockIdx.x*256 + threadIdx.x;
  if (i < n) out[i] = 12345.0f;
}

// ---- weight prep ----
#define NW_ENC (7*24*64*8)   // 86016
#define NW_DEC (4*24*64*8)   // 49152
#define SH_TOTAL (2*NW_ENC + 2*NW_DEC)
#define FWT_TOTAL (32*384 + 384)
#define PREP_TOTAL (NW_ENC + NW_DEC + 32*384 + 384)
__global__ __launch_bounds__(256) void k_prep(const float* __restrict__ ewih,
    const float* __restrict__ ewhh, const float* __restrict__ dwih,
    const float* __restrict__ dwhh, short* __restrict__ ws, float* __restrict__ wf){
  int i = blockIdx.x*256 + threadIdx.x;
  if (i < NW_ENC){
    int e = i & 7, lane = (i>>3) & 63, ct = (i>>9) % 24, ks = i / 12288;
    int k = ks*32 + (lane>>4)*8 + e;
    int col = ct*16 + (lane&15);
    float wv = (k < 65) ? ewih[col*65 + k] : ((k < 96) ? 0.f : ewhh[col*128 + (k-96)]);
    unsigned short hi = f2b(wv);
    ws[i] = (short)hi;
    ws[NW_ENC + i] = (short)f2b(wv - b2f(hi));
  } else if (i < NW_ENC + NW_DEC){
    int j = i - NW_ENC;
    int e = j & 7, lane = (j>>3) & 63, ct = (j>>9) % 24, ks = j / 12288;
    int k = ks*32 + (lane>>4)*8 + e;
    int col = ct*16 + (lane&15);
    float wv = dwhh[col*128 + k];
    unsigned short hi = f2b(wv);
    ws[2*NW_ENC + j] = (short)hi;
    ws[2*NW_ENC + NW_DEC + j] = (short)f2b(wv - b2f(hi));
  } else if (i < NW_ENC + NW_DEC + 32*384){
    int j = i - (NW_ENC + NW_DEC); int k = j/384, n = j%384;
    wf[j] = dwih[n*33 + 1 + k];
  } else if (i < PREP_TOTAL){
    int n = i - (NW_ENC + NW_DEC + 32*384);
    wf[32*384 + n] = dwih[n*33];
  }
}

// emb = tanh(state * fc_w + fc_b)
__global__ __launch_bounds__(256) void k_emb(const float* __restrict__ x,
    const float* __restrict__ w, const float* __restrict__ b, float* __restrict__ emb){
  int idx = blockIdx.x*256 + threadIdx.x;
  if (idx >= ROWS*16) return;
  int j = idx & 15, row = idx >> 4;
  int bb = row / NNODE, n = row % NNODE;
  float s = x[((bb*NT + (NT-1))*NNODE + n)*NF];
  emb[idx] = tanhf(s*w[j] + b[j]);
}

// wave-per-row adjacency
__global__ __launch_bounds__(256) void k_adj(const float* __restrict__ emb,
    const float* __restrict__ Aph, const float* __restrict__ alp,
    float* __restrict__ Abuf, float* __restrict__ rsum){
  int wid = threadIdx.x >> 6, lane = threadIdx.x & 63;
  int row = blockIdx.x*4 + wid;
  int bb = row / NNODE, n = row % NNODE;
  const float4* er = (const float4*)(emb + (size_t)row*16);
  float4 e0 = er[0], e1 = er[1], e2 = er[2], e3 = er[3];
  float d[4];
  #pragma unroll
  for (int q=0;q<4;++q){
    int m = lane + q*64;
    float dd = -1.f;
    if (m < NNODE){
      const float4* em = (const float4*)(emb + (size_t)(bb*NNODE+m)*16);
      float4 m0 = em[0], m1 = em[1], m2 = em[2], m3 = em[3];
      dd = e0.x*m0.x + e0.y*m0.y + e0.z*m0.z + e0.w*m0.w
         + e1.x*m1.x + e1.y*m1.y + e1.z*m1.z + e1.w*m1.w
         + e2.x*m2.x + e2.y*m2.y + e2.z*m2.z + e2.w*m2.w
         + e3.x*m3.x + e3.y*m3.y + e3.z*m3.z + e3.w*m3.w;
      dd = dd > 0.f ? dd : 0.f;
    }
    d[q] = dd;
  }
  int km = 0;
  float vmax = 0.f;
  for (int it=0; it<10; ++it){
    float v = -1.f; int mi = 1<<20;
    #pragma unroll
    for (int q=0;q<4;++q){
      if (d[q] >= 0.f && !((km>>q)&1) && d[q] > v){ v = d[q]; mi = lane + q*64; }
    }
    #pragma unroll
    for (int off=1; off<64; off<<=1){
      float v2 = __shfl_xor(v, off, 64);
      int  i2 = __shfl_xor(mi, off, 64);
      if (v2 > v || (v2 == v && i2 < mi)){ v = v2; mi = i2; }
    }
    if (it == 0) vmax = v;
    if ((mi & 63) == lane) km |= 1 << (mi >> 6);
  }
  float a = sigf(alp[0]);
  float eneg = __expf(-vmax);
  float p[4]; float ps = 0.f;
  #pragma unroll
  for (int q=0;q<4;++q){
    p[q] = 0.f;
    if (d[q] >= 0.f) p[q] = ((km>>q)&1) ? __expf(d[q]-vmax) : eneg;
    ps += p[q];
  }
  #pragma unroll
  for (int off=1; off<64; off<<=1) ps += __shfl_xor(ps, off, 64);
  float inv = (1.f - a)/ps;
  float rs = 0.f;
  #pragma unroll
  for (int q=0;q<4;++q){
    int m = lane + q*64;
    if (m < NNODE){
      float Av = a*Aph[n*NNODE + m] + p[q]*inv;
      Abuf[(size_t)row*LSTR + m] = Av;
      rs += Av;
    }
  }
  if (lane == 0) Abuf[(size_t)row*LSTR + 207] = 0.f;
  #pragma unroll
  for (int off=1; off<64; off<<=1) rs += __shfl_xor(rs, off, 64);
  if (lane == 0) rsum[row] = rs;
}

__global__ __launch_bounds__(256) void k_lam(const float* __restrict__ rsum, float* __restrict__ lam){
  __shared__ float rv[256];
  int b = blockIdx.x, tid = threadIdx.x;
  rv[tid] = (tid < NNODE) ? rsum[b*NNODE+tid] : -1e30f;
  __syncthreads();
  for (int s=128;s>0;s>>=1){ if (tid<s) rv[tid]=fmaxf(rv[tid],rv[tid+s]); __syncthreads(); }
  if (tid==0) lam[b] = fmaxf(rv[0], 1.0f);
}

__global__ __launch_bounds__(256) void k_lap(float* __restrict__ Abuf, const float* __restrict__ lam){
  int idx = blockIdx.x*256 + threadIdx.x;
  if (idx >= NB*NNODE*LSTR) return;
  int b = idx / (NNODE*LSTR);
  int rem = idx % (NNODE*LSTR);
  int n = rem / LSTR, m = rem % LSTR;
  Abuf[idx] = 2.f*Abuf[idx]/lam[b] - (n==m ? 1.f : 0.f);
}

// causal conv(3) + GLU
__global__ __launch_bounds__(256) void k_tcn(const float* __restrict__ x,
    const float* __restrict__ w, const float* __restrict__ bcn, float* __restrict__ tfeat){
  int idx = blockIdx.x*256 + threadIdx.x;
  if (idx >= BTN*32) return;
  int o = idx & 31; int r = idx >> 5;
  int n = r % NNODE, bt = r / NNODE, t = bt % NT, b = bt / NT;
  float t0 = (t>=2)? x[((size_t)(b*NT+t-2)*NNODE+n)*NF] : 0.f;
  float t1 = (t>=1)? x[((size_t)(b*NT+t-1)*NNODE+n)*NF] : 0.f;
  float t2 = x[((size_t)(b*NT+t)*NNODE+n)*NF];
  float P = bcn[o]    + w[o*3]*t0       + w[o*3+1]*t1       + w[o*3+2]*t2;
  float Q = bcn[o+32] + w[(o+32)*3]*t0  + w[(o+32)*3+1]*t1  + w[(o+32)*3+2]*t2;
  tfeat[(size_t)r*32 + o] = P * sigf(Q);
}

__global__ __launch_bounds__(256) void k_thetaBC(const float* __restrict__ tfeat,
    const float* __restrict__ theta, float* __restrict__ P2, float* __restrict__ P1){
  __shared__ float thB[32][33], thC[32][33];
  __shared__ float tf[8][32];
  int tid = threadIdx.x;
  for (int i=tid; i<1024; i+=256){
    int f = i >> 5, o = i & 31;
    thB[o][f] = theta[1024+f*32+o]; thC[o][f] = theta[2048+f*32+o];
  }
  int rl = tid >> 5, o = tid & 31;
  int r = blockIdx.x*8 + rl;
  tf[rl][o] = tfeat[(size_t)r*32 + o];
  __syncthreads();
  float aB=0.f, aC=0.f;
  #pragma unroll
  for (int f=0; f<32; ++f){
    float t = tf[rl][f];
    aB += t*thB[o][f]; aC += t*thC[o][f];
  }
  int n = r % NNODE, bt = r / NNODE, t = bt % NT, b = bt / NT;
  size_t outi = (size_t)(b*NNODE+n)*G3 + t*32 + o;
  P2[outi]=aB; P1[outi]=aC;
}

__global__ __launch_bounds__(256) void k_thetaA(const float* __restrict__ tfeat,
    const float* __restrict__ theta, float* __restrict__ P1){
  __shared__ float thA[32][33];
  __shared__ float tf[8][32];
  int tid = threadIdx.x;
  for (int i=tid; i<1024; i+=256){
    int f = i >> 5, o = i & 31;
    thA[o][f] = theta[f*32+o] - theta[2048+f*32+o];
  }
  int rl = tid >> 5, o = tid & 31;
  int r = blockIdx.x*8 + rl;
  tf[rl][o] = tfeat[(size_t)r*32 + o];
  __syncthreads();
  float aA=0.f;
  #pragma unroll
  for (int f=0; f<32; ++f) aA += tf[rl][f]*thA[o][f];
  int n = r % NNODE, bt = r / NNODE, t = bt % NT, b = bt / NT;
  P1[(size_t)(b*NNODE+n)*G3 + t*32 + o] = aA;
}

// ---- fp32 128x128 GEMM (Chebyshev + ctxGX) ----
__global__ __launch_bounds__(256) void gemm128(
    const float* __restrict__ Ab, int lda, long long sA,
    const float* __restrict__ Bb, long long sB,
    const float* __restrict__ bias,
    const float* __restrict__ Yb, long long sY, float alphaV, float betaV, int do_relu,
    float* __restrict__ Cb, long long sC, int M, int kchunks){
  __shared__ float As[16][132];
  __shared__ float Bs[16][132];
  int bz = blockIdx.z;
  const float* A = Ab + (size_t)bz*sA;
  const float* B = Bb + (size_t)bz*sB;
  float* C = Cb + (size_t)bz*sC;
  int n0 = blockIdx.x*128, m0 = blockIdx.y*128;
  int tid = threadIdx.x, tx = tid & 15, ty = tid >> 4;
  float acc[8][8] = {};
  int ar = tid & 127, ak = (tid >> 7)*8;
  int bk = tid >> 4, bn = (tid & 15)*8;
  for (int kc=0; kc<kchunks; ++kc){
    int k0 = kc*16;
    int m = m0 + ar;
    if (m < M){
      const float* ap = A + (size_t)m*lda + k0 + ak;
      float4 v0 = *(const float4*)ap, v1 = *(const float4*)(ap+4);
      As[ak+0][ar]=v0.x; As[ak+1][ar]=v0.y; As[ak+2][ar]=v0.z; As[ak+3][ar]=v0.w;
      As[ak+4][ar]=v1.x; As[ak+5][ar]=v1.y; As[ak+6][ar]=v1.z; As[ak+7][ar]=v1.w;
    } else {
      #pragma unroll
      for (int j=0;j<8;++j) As[ak+j][ar]=0.f;
    }
    const float* bp = B + (size_t)(k0+bk)*384 + n0 + bn;
    float4 w0_ = *(const float4*)bp, w1_ = *(const float4*)(bp+4);
    *(float4*)&Bs[bk][bn] = w0_; *(float4*)&Bs[bk][bn+4] = w1_;
    __syncthreads();
    #pragma unroll
    for (int kk=0;kk<16;++kk){
      float4 a0 = *(const float4*)&As[kk][ty*8];
      float4 a1 = *(const float4*)&As[kk][ty*8+4];
      float4 b0 = *(const float4*)&Bs[kk][tx*4];
      float4 b1 = *(const float4*)&Bs[kk][64+tx*4];
      float av[8] = {a0.x,a0.y,a0.z,a0.w,a1.x,a1.y,a1.z,a1.w};
      float bv[8] = {b0.x,b0.y,b0.z,b0.w,b1.x,b1.y,b1.z,b1.w};
      #pragma unroll
      for (int i=0;i<8;++i)
        #pragma unroll
        for (int j=0;j<8;++j) acc[i][j] += av[i]*bv[j];
    }
    __syncthreads();
  }
  if (bias){
    float bl[4], bh_[4];
    #pragma unroll
    for (int j=0;j<4;++j){ bl[j]=bias[n0+tx*4+j]; bh_[j]=bias[n0+64+tx*4+j]; }
    #pragma unroll
    for (int i=0;i<8;++i){
      int m2 = m0 + ty*8 + i; if (m2 >= M) continue;
      float4 s0, s1;
      s0.x=acc[i][0]+bl[0]; s0.y=acc[i][1]+bl[1]; s0.z=acc[i][2]+bl[2]; s0.w=acc[i][3]+bl[3];
      s1.x=acc[i][4]+bh_[0]; s1.y=acc[i][5]+bh_[1]; s1.z=acc[i][6]+bh_[2]; s1.w=acc[i][7]+bh_[3];
      *(float4*)&C[(size_t)m2*384 + n0 + tx*4] = s0;
      *(float4*)&C[(size_t)m2*384 + n0 + 64 + tx*4] = s1;
    }
  } else {
    const float* Y = Yb + (size_t)bz*sY;
    #pragma unroll
    for (int i=0;i<8;++i){
      int m2 = m0 + ty*8 + i; if (m2 >= M) continue;
      const float* yr = Y + (size_t)m2*384;
      float* cr = C + (size_t)m2*384;
      float4 y0 = *(const float4*)(yr + n0 + tx*4);
      float4 y1 = *(const float4*)(yr + n0 + 64 + tx*4);
      float4 s0, s1;
      s0.x = alphaV*acc[i][0] + betaV*y0.x; s0.y = alphaV*acc[i][1] + betaV*y0.y;
      s0.z = alphaV*acc[i][2] + betaV*y0.z; s0.w = alphaV*acc[i][3] + betaV*y0.w;
      s1.x = alphaV*acc[i][4] + betaV*y1.x; s1.y = alphaV*acc[i][5] + betaV*y1.y;
      s1.z = alphaV*acc[i][6] + betaV*y1.z; s1.w = alphaV*acc[i][7] + betaV*y1.w;
      if (do_relu){
        s0.x=fmaxf(s0.x,0.f); s0.y=fmaxf(s0.y,0.f); s0.z=fmaxf(s0.z,0.f); s0.w=fmaxf(s0.w,0.f);
        s1.x=fmaxf(s1.x,0.f); s1.y=fmaxf(s1.y,0.f); s1.z=fmaxf(s1.z,0.f); s1.w=fmaxf(s1.w,0.f);
      }
      *(float4*)(cr + n0 + tx*4) = s0;
      *(float4*)(cr + n0 + 64 + tx*4) = s1;
    }
  }
}

// ===================== persistent MFMA encoder+decoder =====================
// 64 rows/block, 512 threads (8 waves). Wave w owns h-cols j in [16w,16w+16).
// h lives in LDS across all 12 enc + 12 dec steps. pred chain in LDS.
#define A_STRIDE 40
#define HSTR 132

#define STAGE_SPLIT(V) { \
    ushort4 hv4, lv4; \
    hv4.x = f2b(V.x); lv4.x = f2b(V.x - b2f(hv4.x)); \
    hv4.y = f2b(V.y); lv4.y = f2b(V.y - b2f(hv4.y)); \
    hv4.z = f2b(V.z); lv4.z = f2b(V.z - b2f(hv4.z)); \
    hv4.w = f2b(V.w); lv4.w = f2b(V.w - b2f(hv4.w)); \
    *(ushort4*)&Ahi[srow*A_STRIDE + skq] = hv4; \
    *(ushort4*)&Alo[srow*A_STRIDE + skq] = lv4; }

#define GATE_KS(WH, WL, KS, ACCR, ACCZ, ACCN) { \
    const int ko = (KS)*24; \
    short8 bRh = *(const short8*)(WH + ((ko + w)*64 + lane)*8); \
    short8 bZh = *(const short8*)(WH + ((ko + 8 + w)*64 + lane)*8); \
    short8 bNh = *(const short8*)(WH + ((ko + 16 + w)*64 + lane)*8); \
    short8 bRl = *(const short8*)(WL + ((ko + w)*64 + lane)*8); \
    short8 bZl = *(const short8*)(WL + ((ko + 8 + w)*64 + lane)*8); \
    short8 bNl = *(const short8*)(WL + ((ko + 16 + w)*64 + lane)*8); \
    _Pragma("unroll") \
    for (int rt=0; rt<4; ++rt){ \
      short8 ah = *(const short8*)&Ahi[rt*16*A_STRIDE + fbase]; \
      short8 al = *(const short8*)&Alo[rt*16*A_STRIDE + fbase]; \
      mm4(ah, al, bRh, bRl, ACCR[rt]); \
      mm4(ah, al, bZh, bZl, ACCZ[rt]); \
      mm4(ah, al, bNh, bNl, ACCN[rt]); \
    } }

__global__ __launch_bounds__(512) void k_encdec(
    const float* __restrict__ ztm,
    const short* __restrict__ WFH, const short* __restrict__ WFL,
    const float* __restrict__ bih, const float* __restrict__ bhh,
    const short* __restrict__ DFH, const short* __restrict__ DFL,
    const float* __restrict__ dbhh, const float* __restrict__ ctxGX,
    const float* __restrict__ w0, const float* __restrict__ ow,
    const float* __restrict__ ob, const float* __restrict__ pred0,
    float* __restrict__ preds_out){
  __shared__ short Ahi[64*A_STRIDE];
  __shared__ short Alo[64*A_STRIDE];
  __shared__ float hl_[64*HSTR];
  __shared__ float psl[8][64];
  __shared__ float predl[64];
  int m0 = blockIdx.x*64;
  int tid = threadIdx.x;
  int w = tid >> 6, lane = tid & 63;
  int g = lane >> 4, c = lane & 15;
  int srow = tid >> 3, skq = (tid & 7)*4;
  int fbase = c*A_STRIDE + g*8;
  int j = (w<<4) + c;
  for (int i = tid; i < 64*HSTR; i += 512) hl_[i] = 0.f;
  if (tid < 64) predl[tid] = pred0[m0 + tid];
  float birv = bih[j], bizv = bih[128+j], binv = bih[256+j];
  float bhrv = bhh[j], bhzv = bhh[128+j], bhnv = bhh[256+j];

  // -------- encoder: 12 steps --------
  for (int t = 0; t < NT; ++t){
    accf4 accR[4] = {}, accZ[4] = {}, accNZ[4] = {}, accNH[4] = {};
    const float* zt = ztm + (size_t)t*ROWS*ZSTR;
    #pragma unroll
    for (int ks=0; ks<3; ++ks){
      __syncthreads();
      int k = ks*32 + skq;
      float4 v = make_float4(0.f,0.f,0.f,0.f);
      if (k < 80) v = *(const float4*)&zt[(size_t)(m0+srow)*ZSTR + k];
      STAGE_SPLIT(v);
      __syncthreads();
      GATE_KS(WFH, WFL, ks, accR, accZ, accNZ);
    }
    #pragma unroll
    for (int ks=3; ks<7; ++ks){
      __syncthreads();
      float4 v = *(const float4*)&hl_[srow*HSTR + (ks-3)*32 + skq];
      STAGE_SPLIT(v);
      __syncthreads();
      GATE_KS(WFH, WFL, ks, accR, accZ, accNH);
    }
    #pragma unroll
    for (int rt=0; rt<4; ++rt){
      #pragma unroll
      for (int i=0;i<4;++i){
        int row = rt*16 + g*4 + i;
        float r_ = sigf(accR[rt][i] + birv + bhrv);
        float z_ = sigf(accZ[rt][i] + bizv + bhzv);
        float n_ = tanhf(accNZ[rt][i] + binv + r_*(accNH[rt][i] + bhnv));
        float ho = hl_[row*HSTR + j];
        hl_[row*HSTR + j] = (1.f - z_)*n_ + z_*ho;
      }
    }
  }

  // -------- decoder: 12 steps --------
  float w0r = w0[j], w0z = w0[128+j], w0n = w0[256+j];
  float bhr = dbhh[j], bhz = dbhh[128+j], bhn = dbhh[256+j];
  float owj = ow[j];
  float obv = ob[0];
  for (int s = 0; s < NT; ++s){
    accf4 accR[4] = {}, accZ[4] = {}, accN[4] = {};
    #pragma unroll
    for (int ks=0; ks<4; ++ks){
      __syncthreads();
      float4 v = *(const float4*)&hl_[srow*HSTR + ks*32 + skq];
      STAGE_SPLIT(v);
      __syncthreads();
      GATE_KS(DFH, DFL, ks, accR, accZ, accN);
    }
    #pragma unroll
    for (int rt=0; rt<4; ++rt){
      #pragma unroll
      for (int i=0;i<4;++i){
        int row = rt*16 + g*4 + i;
        float p = predl[row];
        const float* gx = ctxGX + (size_t)(m0+row)*384;
        float r_ = sigf(gx[j]     + p*w0r + accR[rt][i] + bhr);
        float z_ = sigf(gx[128+j] + p*w0z + accZ[rt][i] + bhz);
        float n_ = tanhf(gx[256+j] + p*w0n + r_*(accN[rt][i] + bhn));
        float ho = hl_[row*HSTR + j];
        float hn = (1.f - z_)*n_ + z_*ho;
        hl_[row*HSTR + j] = hn;
        float psv = hn*owj;
        psv += __shfl_xor(psv, 1, 64);
        psv += __shfl_xor(psv, 2, 64);
        psv += __shfl_xor(psv, 4, 64);
        psv += __shfl_xor(psv, 8, 64);
        if (c == 0) psl[w][row] = psv;
      }
    }
    __syncthreads();
    if (tid < 64){
      float sm = obv;
      #pragma unroll
      for (int w2=0; w2<8; ++w2) sm += psl[w2][tid];
      predl[tid] = sm;
      preds_out[(size_t)s*ROWS + m0 + tid] = sm;
    }
  }
}

// fusion + attn gate, half-wave per row (uniform lanes, no divergence)
__global__ __launch_bounds__(256) void k_zbuild(const float* __restrict__ x,
    const float* __restrict__ S, const float* __restrict__ cw, const float* __restrict__ cb,
    const float* __restrict__ aw, const float* __restrict__ ab,
    float* __restrict__ ztm, float* __restrict__ ctx, float* __restrict__ pred0){
  __shared__ float cwl[416];
  __shared__ float cbl[32];
  __shared__ float awl[65];
  int tid = threadIdx.x;
  for (int i=tid; i<416; i+=256) cwl[i] = cw[i];
  if (tid < 32) cbl[tid] = cb[tid];
  if (tid < 65) awl[tid] = aw[tid];
  __syncthreads();
  int wid = tid >> 6, sel = (tid >> 5) & 1, hl = tid & 31;
  int r = blockIdx.x*8 + wid*2 + sel;
  int n = r % NNODE, bt = r / NNODE, t = bt % NT, b = bt / NT;
  const float* xr = x + (size_t)r*NF;
  float x0 = xr[0];
  float s_ = cbl[hl];
  #pragma unroll
  for (int f=0; f<13; ++f) s_ += xr[1+f]*cwl[hl*13+f];
  float ce = s_ > 0.f ? s_ : 0.f;
  float sv = S[(size_t)(b*NNODE+n)*G3 + t*32 + hl];
  float part = sv*awl[1+hl] + ce*awl[33+hl] + (hl==0 ? x0*awl[0] : 0.f);
  part += __shfl_xor(part, 1, 64);
  part += __shfl_xor(part, 2, 64);
  part += __shfl_xor(part, 4, 64);
  part += __shfl_xor(part, 8, 64);
  part += __shfl_xor(part, 16, 64);
  float attn = sigf(part + ab[0]);
  int i_ = r / NT, tau = r % NT;          // scrambled reshape (B*N, T, 65)
  float* zr = ztm + ((size_t)tau*ROWS + i_)*ZSTR;
  zr[1+hl] = sv*attn;
  zr[33+hl] = ce*attn;                    // hl=31 -> zr[64]
  if (hl == 0) zr[0] = x0*attn;
  if (hl >= 1 && hl <= 15) zr[64+hl] = 0.f;   // pad cols 65..79
  if (t == NT-1){
    ctx[(size_t)(b*NNODE+n)*32 + hl] = ce;
    if (hl == 0) pred0[b*NNODE+n] = x0;
  }
}

__global__ __launch_bounds__(256) void k_out(const float* __restrict__ preds, float* __restrict__ out){
  int idx = blockIdx.x*256 + threadIdx.x;
  if (idx >= NT*ROWS) return;
  int n = idx % NNODE;
  int t2 = idx / NNODE;
  int hor = t2 % NT;
  int b = t2 / NT;
  out[idx] = preds[(size_t)hor*ROWS + b*NNODE + n];
}

extern "C" void kernel_launch(void* const* d_in, const int* in_sizes, int n_in,
                              void* d_out, int out_size, void* d_ws, size_t ws_size,
                              hipStream_t stream){
  const float* x     = (const float*)d_in[0];
  const float* Aph   = (const float*)d_in[1];
  const float* fcw   = (const float*)d_in[2];
  const float* fcb   = (const float*)d_in[3];
  const float* alp   = (const float*)d_in[4];
  const float* cw    = (const float*)d_in[5];
  const float* cb    = (const float*)d_in[6];
  const float* tw    = (const float*)d_in[7];
  const float* tb    = (const float*)d_in[8];
  const float* theta = (const float*)d_in[9];
  const float* aw    = (const float*)d_in[10];
  const float* ab    = (const float*)d_in[11];
  const float* ewih  = (const float*)d_in[12];
  const float* ewhh  = (const float*)d_in[13];
  const float* ebih  = (const float*)d_in[14];
  const float* ebhh  = (const float*)d_in[15];
  const float* dwih  = (const float*)d_in[16];
  const float* dwhh  = (const float*)d_in[17];
  const float* dbih  = (const float*)d_in[18];
  const float* dbhh  = (const float*)d_in[19];
  const float* ow    = (const float*)d_in[20];
  const float* ob    = (const float*)d_in[21];
  float* out = (float*)d_out;

  const size_t SZ_CTX  = (size_t)ROWS*32;
  const size_t SZ_PRED = (size_t)ROWS;
  const size_t SZ_PREDS= (size_t)NT*ROWS;
  const size_t SZ_G    = (size_t)ROWS*G3;
  const size_t SZ_ABUF = (size_t)NB*NNODE*LSTR;
  const size_t SZ_EMB  = (size_t)ROWS*16;
  const size_t SZ_Z    = (size_t)NT*ROWS*ZSTR;   // >= 2*SZ_G

  float* w = (float*)d_ws;
  size_t off = 0;
  auto alloc = [&](size_t nfl){ float* p = w + off; off += nfl; return p; };
  float* ctx   = alloc(SZ_CTX);
  float* pred  = alloc(SZ_PRED);
  float* preds = alloc(SZ_PREDS);
  float* Abuf  = alloc(SZ_ABUF);
  float* emb   = alloc(SZ_EMB);
  float* rsum  = alloc(SZ_PRED);
  float* lam   = alloc((size_t)NB);
  short* wS    = (short*)alloc(SH_TOTAL/2);
  float* wF    = alloc((size_t)FWT_TOTAL);
  float* Sslot = alloc(SZ_G);      // t_feat -> S -> ctxGX
  float* Zzone = alloc(SZ_Z);      // P1 | P2 ; later z
  float* P1 = Zzone;
  float* P2 = Zzone + SZ_G;
  (void)n_in; (void)in_sizes;

  if (ws_size < off*sizeof(float)){    // tripwire: workspace too small
    k_sentinel<<<(out_size+255)/256, 256, 0, stream>>>(out, out_size);
    return;
  }

  const short* WFH = wS;
  const short* WFL = wS + NW_ENC;
  const short* DFH = wS + 2*NW_ENC;
  const short* DFL = wS + 2*NW_ENC + NW_DEC;
  float* dwihT = wF;
  float* w0    = wF + 32*384;

  k_prep<<<(PREP_TOTAL+255)/256, 256, 0, stream>>>(ewih, ewhh, dwih, dwhh, wS, wF);
  float* tfeat = Sslot;
  k_emb<<<(ROWS*16)/256, 256, 0, stream>>>(x, fcw, fcb, emb);
  k_adj<<<ROWS/4, 256, 0, stream>>>(emb, Aph, alp, Abuf, rsum);
  k_lam<<<NB, 256, 0, stream>>>(rsum, lam);
  k_lap<<<(NB*NNODE*LSTR)/256, 256, 0, stream>>>(Abuf, lam);
  k_tcn<<<(BTN*32)/256, 256, 0, stream>>>(x, tw, tb, tfeat);
  k_thetaBC<<<BTN/8, 256, 0, stream>>>(tfeat, theta, P2, P1);
  gemm128<<<dim3(3, 2, NB), 256, 0, stream>>>(Abuf, LSTR, (long long)NNODE*LSTR,
      P1, (long long)NNODE*G3, nullptr,
      P2, (long long)NNODE*G3, 2.f, 1.f, 0,
      P2, (long long)NNODE*G3, NNODE, 13);
  k_thetaA<<<BTN/8, 256, 0, stream>>>(tfeat, theta, P1);
  gemm128<<<dim3(3, 2, NB), 256, 0, stream>>>(Abuf, LSTR, (long long)NNODE*LSTR,
      P2, (long long)NNODE*G3, nullptr,
      P1, (long long)NNODE*G3, 1.f, 1.f, 1,
      Sslot, (long long)NNODE*G3, NNODE, 13);
  k_zbuild<<<BTN/8, 256, 0, stream>>>(x, Sslot, cw, cb, aw, ab, Zzone, ctx, pred);
  float* ctxGX = Sslot;  // S dead after zbuild
  gemm128<<<dim3(3, ROWS/128, 1), 256, 0, stream>>>(
      ctx, 32, 0, dwihT, 0, dbih,
      nullptr, 0, 1.f, 0.f, 0, ctxGX, 0, ROWS, 2);
  k_encdec<<<ROWS/64, 512, 0, stream>>>(Zzone, WFH, WFL, ebih, ebhh,
      DFH, DFL, dbhh, ctxGX, w0, ow, ob, pred, preds);
  k_out<<<(NT*ROWS)/256, 256, 0, stream>>>(preds, out);
}

// Round 9
// 884.062 us; speedup vs baseline: 2.8923x; 1.0239x over previous
//
#include <hip/hip_runtime.h>
#include <math.h>

#define NB 128      // B
#define NT 12       // T
#define NNODE 207   // N
#define NF 14       // F
#define NH 128      // H
#define ROWS (NB*NNODE)      // 26496
#define BTN (NB*NT*NNODE)    // 317952
#define G3 (3*NH)            // 384
#define LSTR 208             // padded Laplacian row stride
#define ZSTR 80              // padded z row stride

typedef __attribute__((ext_vector_type(8))) short short8;   // 8 bf16 = 4 VGPR
typedef __attribute__((ext_vector_type(4))) float accf4;    // MFMA C/D

#define MFMA16 __builtin_amdgcn_mfma_f32_16x16x32_bf16

__device__ __forceinline__ float sigf(float x){ return 1.0f/(1.0f+__expf(-x)); }
__device__ __forceinline__ unsigned short f2b(float f){
  unsigned int u = __float_as_uint(f);
  return (unsigned short)((u + 0x7FFFu + ((u>>16)&1u)) >> 16);
}
__device__ __forceinline__ float b2f(unsigned short h){
  return __uint_as_float(((unsigned int)h) << 16);
}
// split-bf16 3-term product: hi*hi + lo*hi + hi*lo (lo*lo ~2^-16, negligible)
__device__ __forceinline__ void mm3(short8 ah, short8 al, short8 bh, short8 bl, accf4& acc){
  acc = MFMA16(ah, bh, acc, 0,0,0);
  acc = MFMA16(al, bh, acc, 0,0,0);
  acc = MFMA16(ah, bl, acc, 0,0,0);
}

__global__ __launch_bounds__(256) void k_sentinel(float* __restrict__ out, int n){
  int i = blockIdx.x*256 + threadIdx.x;
  if (i < n) out[i] = 12345.0f;
}

// ---- weight prep ----
#define NW_ENC (7*24*64*8)   // 86016
#define NW_DEC (4*24*64*8)   // 49152
#define SH_TOTAL (2*NW_ENC + 2*NW_DEC)
#define FWT_TOTAL (32*384 + 384)
#define PREP_TOTAL (NW_ENC + NW_DEC + 32*384 + 384)
__global__ __launch_bounds__(256) void k_prep(const float* __restrict__ ewih,
    const float* __restrict__ ewhh, const float* __restrict__ dwih,
    const float* __restrict__ dwhh, short* __restrict__ ws, float* __restrict__ wf){
  int i = blockIdx.x*256 + threadIdx.x;
  if (i < NW_ENC){
    int e = i & 7, lane = (i>>3) & 63, ct = (i>>9) % 24, ks = i / 12288;
    int k = ks*32 + (lane>>4)*8 + e;
    int col = ct*16 + (lane&15);
    float wv = (k < 65) ? ewih[col*65 + k] : ((k < 96) ? 0.f : ewhh[col*128 + (k-96)]);
    unsigned short hi = f2b(wv);
    ws[i] = (short)hi;
    ws[NW_ENC + i] = (short)f2b(wv - b2f(hi));
  } else if (i < NW_ENC + NW_DEC){
    int j = i - NW_ENC;
    int e = j & 7, lane = (j>>3) & 63, ct = (j>>9) % 24, ks = j / 12288;
    int k = ks*32 + (lane>>4)*8 + e;
    int col = ct*16 + (lane&15);
    float wv = dwhh[col*128 + k];
    unsigned short hi = f2b(wv);
    ws[2*NW_ENC + j] = (short)hi;
    ws[2*NW_ENC + NW_DEC + j] = (short)f2b(wv - b2f(hi));
  } else if (i < NW_ENC + NW_DEC + 32*384){
    int j = i - (NW_ENC + NW_DEC); int k = j/384, n = j%384;
    wf[j] = dwih[n*33 + 1 + k];
  } else if (i < PREP_TOTAL){
    int n = i - (NW_ENC + NW_DEC + 32*384);
    wf[32*384 + n] = dwih[n*33];
  }
}

// emb = tanh(state * fc_w + fc_b)
__global__ __launch_bounds__(256) void k_emb(const float* __restrict__ x,
    const float* __restrict__ w, const float* __restrict__ b, float* __restrict__ emb){
  int idx = blockIdx.x*256 + threadIdx.x;
  if (idx >= ROWS*16) return;
  int j = idx & 15, row = idx >> 4;
  int bb = row / NNODE, n = row % NNODE;
  float s = x[((bb*NT + (NT-1))*NNODE + n)*NF];
  emb[idx] = tanhf(s*w[j] + b[j]);
}

// wave-per-row adjacency
__global__ __launch_bounds__(256) void k_adj(const float* __restrict__ emb,
    const float* __restrict__ Aph, const float* __restrict__ alp,
    float* __restrict__ Abuf, float* __restrict__ rsum){
  int wid = threadIdx.x >> 6, lane = threadIdx.x & 63;
  int row = blockIdx.x*4 + wid;
  int bb = row / NNODE, n = row % NNODE;
  const float4* er = (const float4*)(emb + (size_t)row*16);
  float4 e0 = er[0], e1 = er[1], e2 = er[2], e3 = er[3];
  float d[4];
  #pragma unroll
  for (int q=0;q<4;++q){
    int m = lane + q*64;
    float dd = -1.f;
    if (m < NNODE){
      const float4* em = (const float4*)(emb + (size_t)(bb*NNODE+m)*16);
      float4 m0 = em[0], m1 = em[1], m2 = em[2], m3 = em[3];
      dd = e0.x*m0.x + e0.y*m0.y + e0.z*m0.z + e0.w*m0.w
         + e1.x*m1.x + e1.y*m1.y + e1.z*m1.z + e1.w*m1.w
         + e2.x*m2.x + e2.y*m2.y + e2.z*m2.z + e2.w*m2.w
         + e3.x*m3.x + e3.y*m3.y + e3.z*m3.z + e3.w*m3.w;
      dd = dd > 0.f ? dd : 0.f;
    }
    d[q] = dd;
  }
  int km = 0;
  float vmax = 0.f;
  for (int it=0; it<10; ++it){
    float v = -1.f; int mi = 1<<20;
    #pragma unroll
    for (int q=0;q<4;++q){
      if (d[q] >= 0.f && !((km>>q)&1) && d[q] > v){ v = d[q]; mi = lane + q*64; }
    }
    #pragma unroll
    for (int off=1; off<64; off<<=1){
      float v2 = __shfl_xor(v, off, 64);
      int  i2 = __shfl_xor(mi, off, 64);
      if (v2 > v || (v2 == v && i2 < mi)){ v = v2; mi = i2; }
    }
    if (it == 0) vmax = v;
    if ((mi & 63) == lane) km |= 1 << (mi >> 6);
  }
  float a = sigf(alp[0]);
  float eneg = __expf(-vmax);
  float p[4]; float ps = 0.f;
  #pragma unroll
  for (int q=0;q<4;++q){
    p[q] = 0.f;
    if (d[q] >= 0.f) p[q] = ((km>>q)&1) ? __expf(d[q]-vmax) : eneg;
    ps += p[q];
  }
  #pragma unroll
  for (int off=1; off<64; off<<=1) ps += __shfl_xor(ps, off, 64);
  float inv = (1.f - a)/ps;
  float rs = 0.f;
  #pragma unroll
  for (int q=0;q<4;++q){
    int m = lane + q*64;
    if (m < NNODE){
      float Av = a*Aph[n*NNODE + m] + p[q]*inv;
      Abuf[(size_t)row*LSTR + m] = Av;
      rs += Av;
    }
  }
  if (lane == 0) Abuf[(size_t)row*LSTR + 207] = 0.f;
  #pragma unroll
  for (int off=1; off<64; off<<=1) rs += __shfl_xor(rs, off, 64);
  if (lane == 0) rsum[row] = rs;
}

__global__ __launch_bounds__(256) void k_lam(const float* __restrict__ rsum, float* __restrict__ lam){
  __shared__ float rv[256];
  int b = blockIdx.x, tid = threadIdx.x;
  rv[tid] = (tid < NNODE) ? rsum[b*NNODE+tid] : -1e30f;
  __syncthreads();
  for (int s=128;s>0;s>>=1){ if (tid<s) rv[tid]=fmaxf(rv[tid],rv[tid+s]); __syncthreads(); }
  if (tid==0) lam[b] = fmaxf(rv[0], 1.0f);
}

__global__ __launch_bounds__(256) void k_lap(float* __restrict__ Abuf, const float* __restrict__ lam){
  int idx = blockIdx.x*256 + threadIdx.x;
  if (idx >= NB*NNODE*LSTR) return;
  int b = idx / (NNODE*LSTR);
  int rem = idx % (NNODE*LSTR);
  int n = rem / LSTR, m = rem % LSTR;
  Abuf[idx] = 2.f*Abuf[idx]/lam[b] - (n==m ? 1.f : 0.f);
}

// causal conv(3) + GLU
__global__ __launch_bounds__(256) void k_tcn(const float* __restrict__ x,
    const float* __restrict__ w, const float* __restrict__ bcn, float* __restrict__ tfeat){
  int idx = blockIdx.x*256 + threadIdx.x;
  if (idx >= BTN*32) return;
  int o = idx & 31; int r = idx >> 5;
  int n = r % NNODE, bt = r / NNODE, t = bt % NT, b = bt / NT;
  float t0 = (t>=2)? x[((size_t)(b*NT+t-2)*NNODE+n)*NF] : 0.f;
  float t1 = (t>=1)? x[((size_t)(b*NT+t-1)*NNODE+n)*NF] : 0.f;
  float t2 = x[((size_t)(b*NT+t)*NNODE+n)*NF];
  float P = bcn[o]    + w[o*3]*t0       + w[o*3+1]*t1       + w[o*3+2]*t2;
  float Q = bcn[o+32] + w[(o+32)*3]*t0  + w[(o+32)*3+1]*t1  + w[(o+32)*3+2]*t2;
  tfeat[(size_t)r*32 + o] = P * sigf(Q);
}

__global__ __launch_bounds__(256) void k_thetaBC(const float* __restrict__ tfeat,
    const float* __restrict__ theta, float* __restrict__ P2, float* __restrict__ P1){
  __shared__ float thB[32][33], thC[32][33];
  __shared__ float tf[8][32];
  int tid = threadIdx.x;
  for (int i=tid; i<1024; i+=256){
    int f = i >> 5, o = i & 31;
    thB[o][f] = theta[1024+f*32+o]; thC[o][f] = theta[2048+f*32+o];
  }
  int rl = tid >> 5, o = tid & 31;
  int r = blockIdx.x*8 + rl;
  tf[rl][o] = tfeat[(size_t)r*32 + o];
  __syncthreads();
  float aB=0.f, aC=0.f;
  #pragma unroll
  for (int f=0; f<32; ++f){
    float t = tf[rl][f];
    aB += t*thB[o][f]; aC += t*thC[o][f];
  }
  int n = r % NNODE, bt = r / NNODE, t = bt % NT, b = bt / NT;
  size_t outi = (size_t)(b*NNODE+n)*G3 + t*32 + o;
  P2[outi]=aB; P1[outi]=aC;
}

__global__ __launch_bounds__(256) void k_thetaA(const float* __restrict__ tfeat,
    const float* __restrict__ theta, float* __restrict__ P1){
  __shared__ float thA[32][33];
  __shared__ float tf[8][32];
  int tid = threadIdx.x;
  for (int i=tid; i<1024; i+=256){
    int f = i >> 5, o = i & 31;
    thA[o][f] = theta[f*32+o] - theta[2048+f*32+o];
  }
  int rl = tid >> 5, o = tid & 31;
  int r = blockIdx.x*8 + rl;
  tf[rl][o] = tfeat[(size_t)r*32 + o];
  __syncthreads();
  float aA=0.f;
  #pragma unroll
  for (int f=0; f<32; ++f) aA += tf[rl][f]*thA[o][f];
  int n = r % NNODE, bt = r / NNODE, t = bt % NT, b = bt / NT;
  P1[(size_t)(b*NNODE+n)*G3 + t*32 + o] = aA;
}

// ---- fp32 128x128 GEMM (Chebyshev + ctxGX) ----
__global__ __launch_bounds__(256) void gemm128(
    const float* __restrict__ Ab, int lda, long long sA,
    const float* __restrict__ Bb, long long sB,
    const float* __restrict__ bias,
    const float* __restrict__ Yb, long long sY, float alphaV, float betaV, int do_relu,
    float* __restrict__ Cb, long long sC, int M, int kchunks){
  __shared__ float As[16][132];
  __shared__ float Bs[16][132];
  int bz = blockIdx.z;
  const float* A = Ab + (size_t)bz*sA;
  const float* B = Bb + (size_t)bz*sB;
  float* C = Cb + (size_t)bz*sC;
  int n0 = blockIdx.x*128, m0 = blockIdx.y*128;
  int tid = threadIdx.x, tx = tid & 15, ty = tid >> 4;
  float acc[8][8] = {};
  int ar = tid & 127, ak = (tid >> 7)*8;
  int bk = tid >> 4, bn = (tid & 15)*8;
  for (int kc=0; kc<kchunks; ++kc){
    int k0 = kc*16;
    int m = m0 + ar;
    if (m < M){
      const float* ap = A + (size_t)m*lda + k0 + ak;
      float4 v0 = *(const float4*)ap, v1 = *(const float4*)(ap+4);
      As[ak+0][ar]=v0.x; As[ak+1][ar]=v0.y; As[ak+2][ar]=v0.z; As[ak+3][ar]=v0.w;
      As[ak+4][ar]=v1.x; As[ak+5][ar]=v1.y; As[ak+6][ar]=v1.z; As[ak+7][ar]=v1.w;
    } else {
      #pragma unroll
      for (int j=0;j<8;++j) As[ak+j][ar]=0.f;
    }
    const float* bp = B + (size_t)(k0+bk)*384 + n0 + bn;
    float4 w0_ = *(const float4*)bp, w1_ = *(const float4*)(bp+4);
    *(float4*)&Bs[bk][bn] = w0_; *(float4*)&Bs[bk][bn+4] = w1_;
    __syncthreads();
    #pragma unroll
    for (int kk=0;kk<16;++kk){
      float4 a0 = *(const float4*)&As[kk][ty*8];
      float4 a1 = *(const float4*)&As[kk][ty*8+4];
      float4 b0 = *(const float4*)&Bs[kk][tx*4];
      float4 b1 = *(const float4*)&Bs[kk][64+tx*4];
      float av[8] = {a0.x,a0.y,a0.z,a0.w,a1.x,a1.y,a1.z,a1.w};
      float bv[8] = {b0.x,b0.y,b0.z,b0.w,b1.x,b1.y,b1.z,b1.w};
      #pragma unroll
      for (int i=0;i<8;++i)
        #pragma unroll
        for (int j=0;j<8;++j) acc[i][j] += av[i]*bv[j];
    }
    __syncthreads();
  }
  if (bias){
    float bl[4], bh_[4];
    #pragma unroll
    for (int j=0;j<4;++j){ bl[j]=bias[n0+tx*4+j]; bh_[j]=bias[n0+64+tx*4+j]; }
    #pragma unroll
    for (int i=0;i<8;++i){
      int m2 = m0 + ty*8 + i; if (m2 >= M) continue;
      float4 s0, s1;
      s0.x=acc[i][0]+bl[0]; s0.y=acc[i][1]+bl[1]; s0.z=acc[i][2]+bl[2]; s0.w=acc[i][3]+bl[3];
      s1.x=acc[i][4]+bh_[0]; s1.y=acc[i][5]+bh_[1]; s1.z=acc[i][6]+bh_[2]; s1.w=acc[i][7]+bh_[3];
      *(float4*)&C[(size_t)m2*384 + n0 + tx*4] = s0;
      *(float4*)&C[(size_t)m2*384 + n0 + 64 + tx*4] = s1;
    }
  } else {
    const float* Y = Yb + (size_t)bz*sY;
    #pragma unroll
    for (int i=0;i<8;++i){
      int m2 = m0 + ty*8 + i; if (m2 >= M) continue;
      const float* yr = Y + (size_t)m2*384;
      float* cr = C + (size_t)m2*384;
      float4 y0 = *(const float4*)(yr + n0 + tx*4);
      float4 y1 = *(const float4*)(yr + n0 + 64 + tx*4);
      float4 s0, s1;
      s0.x = alphaV*acc[i][0] + betaV*y0.x; s0.y = alphaV*acc[i][1] + betaV*y0.y;
      s0.z = alphaV*acc[i][2] + betaV*y0.z; s0.w = alphaV*acc[i][3] + betaV*y0.w;
      s1.x = alphaV*acc[i][4] + betaV*y1.x; s1.y = alphaV*acc[i][5] + betaV*y1.y;
      s1.z = alphaV*acc[i][6] + betaV*y1.z; s1.w = alphaV*acc[i][7] + betaV*y1.w;
      if (do_relu){
        s0.x=fmaxf(s0.x,0.f); s0.y=fmaxf(s0.y,0.f); s0.z=fmaxf(s0.z,0.f); s0.w=fmaxf(s0.w,0.f);
        s1.x=fmaxf(s1.x,0.f); s1.y=fmaxf(s1.y,0.f); s1.z=fmaxf(s1.z,0.f); s1.w=fmaxf(s1.w,0.f);
      }
      *(float4*)(cr + n0 + tx*4) = s0;
      *(float4*)(cr + n0 + 64 + tx*4) = s1;
    }
  }
}

// ===================== persistent MFMA encoder+decoder (v2) =====================
// 32 rows/block (grid 828), 512 threads (8 waves). Wave w owns h-cols [16w,16w+16).
// h in LDS for all 24 steps; double-buffered A staging -> 1 barrier per kstep.
#define A_STRIDE 40
#define ABUFS (32*A_STRIDE)
#define HSTR 132

#define SPLIT_WRITE(BOFF, V) do{ \
    ushort4 hv4, lv4; \
    hv4.x = f2b(V.x); lv4.x = f2b(V.x - b2f(hv4.x)); \
    hv4.y = f2b(V.y); lv4.y = f2b(V.y - b2f(hv4.y)); \
    hv4.z = f2b(V.z); lv4.z = f2b(V.z - b2f(hv4.z)); \
    hv4.w = f2b(V.w); lv4.w = f2b(V.w - b2f(hv4.w)); \
    *(ushort4*)&Ahi[(BOFF) + srow*A_STRIDE + skq] = hv4; \
    *(ushort4*)&Alo[(BOFF) + srow*A_STRIDE + skq] = lv4; \
  }while(0)

#define STAGE_Z(BUF, ZT, KS) do{ if (tid < 256){ \
    int k = (KS)*32 + skq; \
    float4 v = make_float4(0.f,0.f,0.f,0.f); \
    if (k < 80) v = *(const float4*)&(ZT)[(size_t)(m0+srow)*ZSTR + k]; \
    SPLIT_WRITE((BUF)*ABUFS, v); } }while(0)

#define STAGE_H(BUF, KH) do{ if (tid < 256){ \
    float4 v = *(const float4*)&hl_[srow*HSTR + (KH)*32 + skq]; \
    SPLIT_WRITE((BUF)*ABUFS, v); } }while(0)

#define GATE2(BUF, WH, WL, KS, ACCR, ACCZ, ACCN) do{ \
    const int ko = (KS)*24; \
    short8 bRh = *(const short8*)(WH + ((ko + w)*64 + lane)*8); \
    short8 bZh = *(const short8*)(WH + ((ko + 8 + w)*64 + lane)*8); \
    short8 bNh = *(const short8*)(WH + ((ko + 16 + w)*64 + lane)*8); \
    short8 bRl = *(const short8*)(WL + ((ko + w)*64 + lane)*8); \
    short8 bZl = *(const short8*)(WL + ((ko + 8 + w)*64 + lane)*8); \
    short8 bNl = *(const short8*)(WL + ((ko + 16 + w)*64 + lane)*8); \
    _Pragma("unroll") \
    for (int rt=0; rt<2; ++rt){ \
      short8 ah = *(const short8*)&Ahi[(BUF)*ABUFS + rt*16*A_STRIDE + fbase]; \
      short8 al = *(const short8*)&Alo[(BUF)*ABUFS + rt*16*A_STRIDE + fbase]; \
      mm3(ah, al, bRh, bRl, ACCR[rt]); \
      mm3(ah, al, bZh, bZl, ACCZ[rt]); \
      mm3(ah, al, bNh, bNl, ACCN[rt]); \
    } }while(0)

__global__ __launch_bounds__(512) void k_encdec(
    const float* __restrict__ ztm,
    const short* __restrict__ WFH, const short* __restrict__ WFL,
    const float* __restrict__ bih, const float* __restrict__ bhh,
    const short* __restrict__ DFH, const short* __restrict__ DFL,
    const float* __restrict__ dbhh, const float* __restrict__ ctxGX,
    const float* __restrict__ w0, const float* __restrict__ ow,
    const float* __restrict__ ob, const float* __restrict__ pred0,
    float* __restrict__ preds_out){
  __shared__ short Ahi[2*ABUFS];
  __shared__ short Alo[2*ABUFS];
  __shared__ float hl_[32*HSTR];
  __shared__ float psl[8][32];
  __shared__ float predl[32];
  int m0 = blockIdx.x*32;
  int tid = threadIdx.x;
  int w = tid >> 6, lane = tid & 63;
  int g = lane >> 4, c = lane & 15;
  int srow = tid >> 3, skq = (tid & 7)*4;   // tid<256: rows 0..31, k-chunks of 4
  int fbase = c*A_STRIDE + g*8;
  int j = (w<<4) + c;
  for (int i = tid; i < 32*HSTR; i += 512) hl_[i] = 0.f;
  if (tid < 32) predl[tid] = pred0[m0 + tid];
  float birv = bih[j], bizv = bih[128+j], binv = bih[256+j];
  float bhrv = bhh[j], bhzv = bhh[128+j], bhnv = bhh[256+j];

  // -------- encoder: 12 steps, 7 ksteps each, double-buffered --------
  for (int t = 0; t < NT; ++t){
    accf4 accR[2] = {}, accZ[2] = {}, accNZ[2] = {}, accNH[2] = {};
    const float* zt = ztm + (size_t)t*ROWS*ZSTR;
    STAGE_Z(0, zt, 0);
    #pragma unroll
    for (int ks=0; ks<7; ++ks){
      __syncthreads();
      if (ks < 2)      STAGE_Z((ks+1)&1, zt, ks+1);
      else if (ks < 6) STAGE_H((ks+1)&1, ks-2);      // kstep ks+1 -> h chunk ks+1-3
      if (ks < 3) GATE2(ks&1, WFH, WFL, ks, accR, accZ, accNZ);
      else        GATE2(ks&1, WFH, WFL, ks, accR, accZ, accNH);
    }
    #pragma unroll
    for (int rt=0; rt<2; ++rt){
      #pragma unroll
      for (int i=0;i<4;++i){
        int row = rt*16 + g*4 + i;
        float r_ = sigf(accR[rt][i] + birv + bhrv);
        float z_ = sigf(accZ[rt][i] + bizv + bhzv);
        float n_ = tanhf(accNZ[rt][i] + binv + r_*(accNH[rt][i] + bhnv));
        float ho = hl_[row*HSTR + j];
        hl_[row*HSTR + j] = (1.f - z_)*n_ + z_*ho;
      }
    }
    __syncthreads();   // hl_ stable before next step's staging
  }

  // -------- decoder: 12 steps, 4 ksteps each --------
  float w0r = w0[j], w0z = w0[128+j], w0n = w0[256+j];
  float bhr = dbhh[j], bhz = dbhh[128+j], bhn = dbhh[256+j];
  float owj = ow[j];
  float obv = ob[0];
  for (int s = 0; s < NT; ++s){
    accf4 accR[2] = {}, accZ[2] = {}, accN[2] = {};
    STAGE_H(0, 0);
    #pragma unroll
    for (int ks=0; ks<4; ++ks){
      __syncthreads();
      if (ks < 3) STAGE_H((ks+1)&1, ks+1);
      GATE2(ks&1, DFH, DFL, ks, accR, accZ, accN);
    }
    #pragma unroll
    for (int rt=0; rt<2; ++rt){
      #pragma unroll
      for (int i=0;i<4;++i){
        int row = rt*16 + g*4 + i;
        float p = predl[row];
        const float* gx = ctxGX + (size_t)(m0+row)*384;
        float r_ = sigf(gx[j]     + p*w0r + accR[rt][i] + bhr);
        float z_ = sigf(gx[128+j] + p*w0z + accZ[rt][i] + bhz);
        float n_ = tanhf(gx[256+j] + p*w0n + r_*(accN[rt][i] + bhn));
        float ho = hl_[row*HSTR + j];
        float hn = (1.f - z_)*n_ + z_*ho;
        hl_[row*HSTR + j] = hn;
        float psv = hn*owj;
        psv += __shfl_xor(psv, 1, 64);
        psv += __shfl_xor(psv, 2, 64);
        psv += __shfl_xor(psv, 4, 64);
        psv += __shfl_xor(psv, 8, 64);
        if (c == 0) psl[w][row] = psv;
      }
    }
    __syncthreads();
    if (tid < 32){
      float sm = obv;
      #pragma unroll
      for (int w2=0; w2<8; ++w2) sm += psl[w2][tid];
      predl[tid] = sm;
      preds_out[(size_t)s*ROWS + m0 + tid] = sm;
    }
    __syncthreads();   // predl + hl_ stable before next step
  }
}

// fusion + attn gate, half-wave per row (uniform lanes, no divergence)
__global__ __launch_bounds__(256) void k_zbuild(const float* __restrict__ x,
    const float* __restrict__ S, const float* __restrict__ cw, const float* __restrict__ cb,
    const float* __restrict__ aw, const float* __restrict__ ab,
    float* __restrict__ ztm, float* __restrict__ ctx, float* __restrict__ pred0){
  __shared__ float cwl[416];
  __shared__ float cbl[32];
  __shared__ float awl[65];
  int tid = threadIdx.x;
  for (int i=tid; i<416; i+=256) cwl[i] = cw[i];
  if (tid < 32) cbl[tid] = cb[tid];
  if (tid < 65) awl[tid] = aw[tid];
  __syncthreads();
  int wid = tid >> 6, sel = (tid >> 5) & 1, hl = tid & 31;
  int r = blockIdx.x*8 + wid*2 + sel;
  int n = r % NNODE, bt = r / NNODE, t = bt % NT, b = bt / NT;
  const float* xr = x + (size_t)r*NF;
  float x0 = xr[0];
  float s_ = cbl[hl];
  #pragma unroll
  for (int f=0; f<13; ++f) s_ += xr[1+f]*cwl[hl*13+f];
  float ce = s_ > 0.f ? s_ : 0.f;
  float sv = S[(size_t)(b*NNODE+n)*G3 + t*32 + hl];
  float part = sv*awl[1+hl] + ce*awl[33+hl] + (hl==0 ? x0*awl[0] : 0.f);
  part += __shfl_xor(part, 1, 64);
  part += __shfl_xor(part, 2, 64);
  part += __shfl_xor(part, 4, 64);
  part += __shfl_xor(part, 8, 64);
  part += __shfl_xor(part, 16, 64);
  float attn = sigf(part + ab[0]);
  int i_ = r / NT, tau = r % NT;          // scrambled reshape (B*N, T, 65)
  float* zr = ztm + ((size_t)tau*ROWS + i_)*ZSTR;
  zr[1+hl] = sv*attn;
  zr[33+hl] = ce*attn;                    // hl=31 -> zr[64]
  if (hl == 0) zr[0] = x0*attn;
  if (hl >= 1 && hl <= 15) zr[64+hl] = 0.f;   // pad cols 65..79
  if (t == NT-1){
    ctx[(size_t)(b*NNODE+n)*32 + hl] = ce;
    if (hl == 0) pred0[b*NNODE+n] = x0;
  }
}

__global__ __launch_bounds__(256) void k_out(const float* __restrict__ preds, float* __restrict__ out){
  int idx = blockIdx.x*256 + threadIdx.x;
  if (idx >= NT*ROWS) return;
  int n = idx % NNODE;
  int t2 = idx / NNODE;
  int hor = t2 % NT;
  int b = t2 / NT;
  out[idx] = preds[(size_t)hor*ROWS + b*NNODE + n];
}

extern "C" void kernel_launch(void* const* d_in, const int* in_sizes, int n_in,
                              void* d_out, int out_size, void* d_ws, size_t ws_size,
                              hipStream_t stream){
  const float* x     = (const float*)d_in[0];
  const float* Aph   = (const float*)d_in[1];
  const float* fcw   = (const float*)d_in[2];
  const float* fcb   = (const float*)d_in[3];
  const float* alp   = (const float*)d_in[4];
  const float* cw    = (const float*)d_in[5];
  const float* cb    = (const float*)d_in[6];
  const float* tw    = (const float*)d_in[7];
  const float* tb    = (const float*)d_in[8];
  const float* theta = (const float*)d_in[9];
  const float* aw    = (const float*)d_in[10];
  const float* ab    = (const float*)d_in[11];
  const float* ewih  = (const float*)d_in[12];
  const float* ewhh  = (const float*)d_in[13];
  const float* ebih  = (const float*)d_in[14];
  const float* ebhh  = (const float*)d_in[15];
  const float* dwih  = (const float*)d_in[16];
  const float* dwhh  = (const float*)d_in[17];
  const float* dbih  = (const float*)d_in[18];
  const float* dbhh  = (const float*)d_in[19];
  const float* ow    = (const float*)d_in[20];
  const float* ob    = (const float*)d_in[21];
  float* out = (float*)d_out;

  const size_t SZ_CTX  = (size_t)ROWS*32;
  const size_t SZ_PRED = (size_t)ROWS;
  const size_t SZ_PREDS= (size_t)NT*ROWS;
  const size_t SZ_G    = (size_t)ROWS*G3;
  const size_t SZ_ABUF = (size_t)NB*NNODE*LSTR;
  const size_t SZ_EMB  = (size_t)ROWS*16;
  const size_t SZ_Z    = (size_t)NT*ROWS*ZSTR;   // >= 2*SZ_G

  float* w = (float*)d_ws;
  size_t off = 0;
  auto alloc = [&](size_t nfl){ float* p = w + off; off += nfl; return p; };
  float* ctx   = alloc(SZ_CTX);
  float* pred  = alloc(SZ_PRED);
  float* preds = alloc(SZ_PREDS);
  float* Abuf  = alloc(SZ_ABUF);
  float* emb   = alloc(SZ_EMB);
  float* rsum  = alloc(SZ_PRED);
  float* lam   = alloc((size_t)NB);
  short* wS    = (short*)alloc(SH_TOTAL/2);
  float* wF    = alloc((size_t)FWT_TOTAL);
  float* Sslot = alloc(SZ_G);      // t_feat -> S -> ctxGX
  float* Zzone = alloc(SZ_Z);      // P1 | P2 ; later z
  float* P1 = Zzone;
  float* P2 = Zzone + SZ_G;
  (void)n_in; (void)in_sizes;

  if (ws_size < off*sizeof(float)){    // tripwire: workspace too small
    k_sentinel<<<(out_size+255)/256, 256, 0, stream>>>(out, out_size);
    return;
  }

  const short* WFH = wS;
  const short* WFL = wS + NW_ENC;
  const short* DFH = wS + 2*NW_ENC;
  const short* DFL = wS + 2*NW_ENC + NW_DEC;
  float* dwihT = wF;
  float* w0    = wF + 32*384;

  k_prep<<<(PREP_TOTAL+255)/256, 256, 0, stream>>>(ewih, ewhh, dwih, dwhh, wS, wF);
  float* tfeat = Sslot;
  k_emb<<<(ROWS*16)/256, 256, 0, stream>>>(x, fcw, fcb, emb);
  k_adj<<<ROWS/4, 256, 0, stream>>>(emb, Aph, alp, Abuf, rsum);
  k_lam<<<NB, 256, 0, stream>>>(rsum, lam);
  k_lap<<<(NB*NNODE*LSTR)/256, 256, 0, stream>>>(Abuf, lam);
  k_tcn<<<(BTN*32)/256, 256, 0, stream>>>(x, tw, tb, tfeat);
  k_thetaBC<<<BTN/8, 256, 0, stream>>>(tfeat, theta, P2, P1);
  gemm128<<<dim3(3, 2, NB), 256, 0, stream>>>(Abuf, LSTR, (long long)NNODE*LSTR,
      P1, (long long)NNODE*G3, nullptr,
      P2, (long long)NNODE*G3, 2.f, 1.f, 0,
      P2, (long long)NNODE*G3, NNODE, 13);
  k_thetaA<<<BTN/8, 256, 0, stream>>>(tfeat, theta, P1);
  gemm128<<<dim3(3, 2, NB), 256, 0, stream>>>(Abuf, LSTR, (long long)NNODE*LSTR,
      P2, (long long)NNODE*G3, nullptr,
      P1, (long long)NNODE*G3, 1.f, 1.f, 1,
      Sslot, (long long)NNODE*G3, NNODE, 13);
  k_zbuild<<<BTN/8, 256, 0, stream>>>(x, Sslot, cw, cb, aw, ab, Zzone, ctx, pred);
  float* ctxGX = Sslot;  // S dead after zbuild
  gemm128<<<dim3(3, ROWS/128, 1), 256, 0, stream>>>(
      ctx, 32, 0, dwihT, 0, dbih,
      nullptr, 0, 1.f, 0.f, 0, ctxGX, 0, ROWS, 2);
  k_encdec<<<ROWS/32, 512, 0, stream>>>(Zzone, WFH, WFL, ebih, ebhh,
      DFH, DFL, dbhh, ctxGX, w0, ow, ob, pred, preds);
  k_out<<<(NT*ROWS)/256, 256, 0, stream>>>(preds, out);
}